// Round 11
// baseline (7195.473 us; speedup 1.0000x reference)
//
#include <hip/hip_runtime.h>
#include <hip/hip_bf16.h>
#include <cstdint>

using bf16 = __hip_bfloat16;
#define DI __device__ __forceinline__

DI float b2f(bf16 v){ return __bfloat162float(v); }
DI float us2f(unsigned short u){ bf16 t; *reinterpret_cast<unsigned short*>(&t) = u; return __bfloat162float(t); }

// R21: R20 (PASS 5.49ms) + two kfused_g2 fixes:
//  - nm stride C+1: kills the 16-way LDS bank conflict on atomicMax
//    (stride 256 put all lanes in 4 banks; +1 spreads by node index)
//  - k-loop unroll 4 (deeper W2 L2-prefetch; was issue-stalled at 24% VALU)
// Identical arithmetic -> absmax 0.015625. Output FLOAT32.

// ---------------- dtype detection on pos (~N(0,1)) ----------------
__global__ void kdetect(const unsigned short* __restrict__ pos_u, int* __restrict__ flag){
  __shared__ int cE, cO;
  if (threadIdx.x == 0){ cE = 0; cO = 0; }
  __syncthreads();
  int pe = 0, po = 0;
  for (int i = threadIdx.x; i < 2048; i += 256){
    float ve = fabsf(us2f(pos_u[2*i]));
    float vo = fabsf(us2f(pos_u[2*i + 1]));
    if (ve > 1e-4f && ve < 50.f) pe++;
    if (vo > 1e-4f && vo < 50.f) po++;
  }
  atomicAdd(&cE, pe);
  atomicAdd(&cO, po);
  __syncthreads();
  if (threadIdx.x == 0)
    flag[0] = (2*cE < cO) ? 1 : 0;   // 1 => inputs are f32
}

// ---------------- normalize all float inputs to f32 ----------------
struct CEnt { const void* s; float* d; int n; };
struct CTab { CEnt e[39]; };
__global__ void kconv(CTab tab, const int* __restrict__ flag){
  CEnt en = tab.e[blockIdx.y];
  const bool isf32 = (flag[0] != 0);
  for (int i = blockIdx.x*256 + threadIdx.x; i < en.n; i += gridDim.x*256)
    en.d[i] = isf32 ? ((const float*)en.s)[i] : b2f(((const bf16*)en.s)[i]);
}

// ---------------- pack x_in = [pos | feat]  [N][64] ----------------
__global__ void kpack0(const float* __restrict__ posf, const float* __restrict__ featf,
                       float* __restrict__ x0, int Nn){
  int i = blockIdx.x*256 + threadIdx.x;
  if (i >= Nn*64) return;
  int n = i >> 6, c = i & 63;
  x0[i] = (c < 3) ? posf[(size_t)n*3 + c] : featf[(size_t)n*61 + (c-3)];
}

// ---------------- W1d = W1top - W1bot ----------------
__global__ void kwd(const float* __restrict__ W1, float* __restrict__ W1d, int CPC){
  int i = blockIdx.x*256 + threadIdx.x;
  if (i < CPC) W1d[i] = W1[i] - W1[CPC + i];
}

// ---------------- graph partition ----------------
__global__ void kgptr(const int* __restrict__ batch, int Nn, int* __restrict__ gptr){
  int g = threadIdx.x;
  if (g > 8) return;
  if (g == 8){ gptr[8] = Nn; return; }
  int lo = 0, hi = Nn;
  while (lo < hi){ int mid = (lo + hi) >> 1; if (batch[mid] < g) lo = mid + 1; else hi = mid; }
  gptr[g] = lo;
}

// ---------------- per-graph heatmap column sums ----------------
__global__ void khs(const float* __restrict__ hmf, const int* __restrict__ gptr,
                    float* __restrict__ hs){
  int g = blockIdx.x;
  int lane = threadIdx.x % 24, slice = threadIdx.x / 24;
  __shared__ float part[10][24];
  if (threadIdx.x < 240){
    int s = gptr[g], e = gptr[g+1];
    float acc = 0.f;
    for (int n = s + slice; n < e; n += 10) acc += hmf[(size_t)n*24 + lane];
    part[slice][lane] = acc;
  }
  __syncthreads();
  if (threadIdx.x < 24){
    float a = 0.f;
    for (int i = 0; i < 10; ++i) a += part[i][threadIdx.x];
    hs[g*24 + threadIdx.x] = a;
  }
}

// ---------------- parallel counting sort of edges by dst (64 blocks) ----------------
#define NB_SORT 64
#define SORT_BINS 8192
__global__ void khist(const int* __restrict__ dst, int E, int Nn, int* __restrict__ part){
  int b = blockIdx.x;
  int per = (E + NB_SORT - 1) / NB_SORT;
  int s = b*per, e_end = s + per; if (e_end > E) e_end = E;
  __shared__ int h[SORT_BINS];
  for (int base = 0; base < Nn; base += SORT_BINS){
    for (int i = threadIdx.x; i < SORT_BINS; i += 256) h[i] = 0;
    __syncthreads();
    for (int e = s + threadIdx.x; e < e_end; e += 256){
      int d = dst[e] - base;
      if (d >= 0 && d < SORT_BINS) atomicAdd(&h[d], 1);
    }
    __syncthreads();
    int lim = Nn - base; if (lim > SORT_BINS) lim = SORT_BINS;
    for (int i = threadIdx.x; i < lim; i += 256) part[(size_t)b*Nn + base + i] = h[i];
    __syncthreads();
  }
}
__global__ void kcnt(const int* __restrict__ part, int Nn, int* __restrict__ cnt){
  int n = blockIdx.x*256 + threadIdx.x; if (n >= Nn) return;
  int s = 0;
  for (int b = 0; b < NB_SORT; ++b) s += part[(size_t)b*Nn + n];
  cnt[n] = s;
}
__global__ void kpre(int* part, int Nn){
  int n = blockIdx.x*256 + threadIdx.x; if (n >= Nn) return;
  int run = 0;
  for (int b = 0; b < NB_SORT; ++b){
    int v = part[(size_t)b*Nn + n];
    part[(size_t)b*Nn + n] = run;
    run += v;
  }
}
__global__ void kscan(const int* __restrict__ cnt, int Nn, int* __restrict__ rp){
  __shared__ int buf[256];
  __shared__ int carry;
  int t = threadIdx.x;
  if (t == 0) carry = 0;
  __syncthreads();
  for (int base = 0; base < Nn; base += 256){
    int v = (base + t < Nn) ? cnt[base + t] : 0;
    buf[t] = v;
    __syncthreads();
    for (int off = 1; off < 256; off <<= 1){
      int x = (t >= off) ? buf[t - off] : 0;
      __syncthreads();
      buf[t] += x;
      __syncthreads();
    }
    if (base + t < Nn) rp[base + t] = carry + buf[t] - v;
    __syncthreads();
    if (t == 255) carry += buf[255];
    __syncthreads();
  }
  if (t == 0) rp[Nn] = carry;
}
__global__ void kscatter(const int* __restrict__ dst, int E, int Nn,
                         const int* __restrict__ part, const int* __restrict__ rp,
                         int* __restrict__ eidx){
  int b = blockIdx.x;
  int per = (E + NB_SORT - 1) / NB_SORT;
  int s = b*per, e_end = s + per; if (e_end > E) e_end = E;
  __shared__ int cur[SORT_BINS];
  for (int base = 0; base < Nn; base += SORT_BINS){
    for (int i = threadIdx.x; i < SORT_BINS; i += 256) cur[i] = 0;
    __syncthreads();
    for (int e = s + threadIdx.x; e < e_end; e += 256){
      int d = dst[e] - base;
      if (d >= 0 && d < SORT_BINS){
        int lr = atomicAdd(&cur[d], 1);
        eidx[rp[base + d] + part[(size_t)b*Nn + base + d] + lr] = e;
      }
    }
    __syncthreads();
  }
}

// ======== FAST PATH (all f32) ========

// node GEMMs (f32): uu = x@W1d + b1 ; vv = x@W1bot
template<int CP, int C>
__launch_bounds__(256)
__global__ void knode_f32(const float* __restrict__ W1d, const float* __restrict__ W1b,
                          const float* __restrict__ b1, const float* __restrict__ x,
                          float* __restrict__ uu, float* __restrict__ vv, int Nn){
  constexpr int NP = C / 64;
  __shared__ float A[16][CP + 1];
  int t = threadIdx.x, el = t & 15, grp = t >> 4;
  int r0 = blockIdx.x * 16;
  for (int idx = t; idx < 16*CP; idx += 256){
    int r = idx / CP, k = idx - r*CP;
    int rr = r0 + r;
    A[r][k] = (rr < Nn) ? x[(size_t)rr*CP + k] : 0.f;
  }
  __syncthreads();
  float au[NP][4], av[NP][4];
  #pragma unroll
  for (int p = 0; p < NP; ++p)
    #pragma unroll
    for (int i = 0; i < 4; ++i){
      au[p][i] = b1[p*64 + grp*4 + i];
      av[p][i] = 0.f;
    }
  #pragma unroll 2
  for (int k = 0; k < CP; ++k){
    float a = A[el][k];
    #pragma unroll
    for (int p = 0; p < NP; ++p){
      float4 wd = *reinterpret_cast<const float4*>(&W1d[(size_t)k*C + p*64 + grp*4]);
      float4 wb = *reinterpret_cast<const float4*>(&W1b[(size_t)k*C + p*64 + grp*4]);
      au[p][0] = fmaf(a, wd.x, au[p][0]); au[p][1] = fmaf(a, wd.y, au[p][1]);
      au[p][2] = fmaf(a, wd.z, au[p][2]); au[p][3] = fmaf(a, wd.w, au[p][3]);
      av[p][0] = fmaf(a, wb.x, av[p][0]); av[p][1] = fmaf(a, wb.y, av[p][1]);
      av[p][2] = fmaf(a, wb.z, av[p][2]); av[p][3] = fmaf(a, wb.w, av[p][3]);
    }
  }
  int rr = r0 + el;
  if (rr < Nn){
    #pragma unroll
    for (int p = 0; p < NP; ++p){
      int c = p*64 + grp*4;
      float4 ou; ou.x = au[p][0]; ou.y = au[p][1]; ou.z = au[p][2]; ou.w = au[p][3];
      float4 ov; ov.x = av[p][0]; ov.y = av[p][1]; ov.z = av[p][2]; ov.w = av[p][3];
      *reinterpret_cast<float4*>(&uu[(size_t)rr*C + c]) = ou;
      *reinterpret_cast<float4*>(&vv[(size_t)rr*C + c]) = ov;
    }
  }
}

// BN1 stats: sum/sumsq of relu(uu_i + vv_j) over all edges, per channel.
template<int C>
__launch_bounds__(256)
__global__ void kh1stats(const float* __restrict__ uu, const float* __restrict__ vv,
                         const int* __restrict__ src, const int* __restrict__ dst,
                         const int* __restrict__ eidx, int E, float* __restrict__ statp)
{
  constexpr int CLOG  = (C==64)?6:(C==128)?7:8;
  constexpr int RSTEP = 256 >> CLOG;
  const int t = threadIdx.x;
  const int kcol = t & (C-1), rb = t >> CLOG;
  int per = (E + gridDim.x - 1) / gridDim.x;
  int s0 = blockIdx.x * per;
  int s1 = s0 + per; if (s1 > E) s1 = E;
  float sa = 0.f, qa = 0.f;
  for (int es = s0 + rb; es < s1; es += RSTEP){
    int e = eidx[es];
    int i = dst[e], j = src[e];
    float a = fmaxf(uu[(size_t)i*C + kcol] + vv[(size_t)j*C + kcol], 0.f);
    sa += a; qa += a*a;
  }
  __shared__ float red[256];
  red[t] = sa;
  __syncthreads();
  if (t < C){
    float x = 0.f;
    #pragma unroll
    for (int r = 0; r < RSTEP; ++r) x += red[t + r*C];
    statp[(size_t)blockIdx.x*2*C + t] = x;
  }
  __syncthreads();
  red[t] = qa;
  __syncthreads();
  if (t < C){
    float x = 0.f;
    #pragma unroll
    for (int r = 0; r < RSTEP; ++r) x += red[t + r*C];
    statp[(size_t)blockIdx.x*2*C + C + t] = x;
  }
}

// fused layer-2 (f32, TE=32, EPL=2): gather H1, GEMM, stats, per-node max
// via LDS int atomicMax. nm stride C+1 (bank-conflict fix).
template<int C>
__launch_bounds__(256)
__global__ void kfused_g2(const float* __restrict__ W2, const float* __restrict__ b2,
                          const float* __restrict__ sc1, const float* __restrict__ sh1,
                          const float* __restrict__ uu, const float* __restrict__ vv,
                          const int* __restrict__ src, const int* __restrict__ dst,
                          const int* __restrict__ eidx, const int* __restrict__ rp,
                          int Nn, float* __restrict__ nodemax, float* __restrict__ statp)
{
  constexpr int NT  = 16;
  constexpr int TE  = 32;
  constexpr int EPL = 2;
  constexpr int NP  = C / 64;
  constexpr int CS  = C + 1;           // padded stride for nm
  __shared__ float H1[TE][C + 1];
  __shared__ int   nm[NT*CS];
  __shared__ float red[16][64];
  __shared__ int Si[TE], Sj[TE], LNs[TE];

  int t = threadIdx.x, el = t & 15, grp = t >> 4;
  int n0 = blockIdx.x * NT;
  int e_begin = rp[n0];
  int e_end   = rp[n0 + NT];

  for (int i = t; i < NT*CS; i += 256) nm[i] = 0;

  float sv[NP][4], qv[NP][4];
  #pragma unroll
  for (int p = 0; p < NP; ++p)
    #pragma unroll
    for (int i = 0; i < 4; ++i){ sv[p][i] = 0.f; qv[p][i] = 0.f; }

  for (int tile = e_begin; tile < e_end; tile += TE){
    int nrows = e_end - tile; if (nrows > TE) nrows = TE;
    __syncthreads();                 // prev tile's H1 readers + nm init done
    if (t < TE){
      if (t < nrows){
        int e = eidx[tile + t];
        int d_ = dst[e];
        Si[t] = d_; Sj[t] = src[e];
        int lnv = d_ - n0;
        LNs[t] = (lnv < 0) ? 0 : (lnv > NT-1 ? NT-1 : lnv);
      } else { Si[t] = 0; Sj[t] = 0; LNs[t] = 0; }
    }
    __syncthreads();
    // H1 gather
    for (int idx = t; idx < TE*C; idx += 256){
      int r = idx / C, c = idx - r*C;
      float v = 0.f;
      if (r < nrows){
        int ii = Si[r], jj = Sj[r];
        v = fmaxf(uu[(size_t)ii*C + c] + vv[(size_t)jj*C + c], 0.f) * sc1[c] + sh1[c];
      }
      H1[r][c] = v;
    }
    __syncthreads();
    // layer-2 GEMM (EPL=2) + stats + per-node atomicMax
    float acc[NP][EPL][4];
    #pragma unroll
    for (int p = 0; p < NP; ++p)
      #pragma unroll
      for (int i = 0; i < 4; ++i){
        float b = b2[p*64 + grp*4 + i];
        #pragma unroll
        for (int q = 0; q < EPL; ++q) acc[p][q][i] = b;
      }
    #pragma unroll 4
    for (int k = 0; k < C; ++k){
      float a[EPL];
      #pragma unroll
      for (int q = 0; q < EPL; ++q) a[q] = H1[el + q*16][k];
      #pragma unroll
      for (int p = 0; p < NP; ++p){
        float4 w = *reinterpret_cast<const float4*>(&W2[(size_t)k*C + p*64 + grp*4]);
        #pragma unroll
        for (int q = 0; q < EPL; ++q){
          acc[p][q][0] = fmaf(a[q], w.x, acc[p][q][0]);
          acc[p][q][1] = fmaf(a[q], w.y, acc[p][q][1]);
          acc[p][q][2] = fmaf(a[q], w.z, acc[p][q][2]);
          acc[p][q][3] = fmaf(a[q], w.w, acc[p][q][3]);
        }
      }
    }
    #pragma unroll
    for (int q = 0; q < EPL; ++q){
      int row = el + q*16;
      if (row < nrows){
        int base = LNs[row]*CS;
        #pragma unroll
        for (int p = 0; p < NP; ++p){
          int c = p*64 + grp*4;
          #pragma unroll
          for (int i = 0; i < 4; ++i){
            float v = fmaxf(acc[p][q][i], 0.f);
            sv[p][i] += v; qv[p][i] += v*v;
            atomicMax(&nm[base + c + i], __float_as_int(v));
          }
        }
      }
    }
  }
  __syncthreads();
  for (int idx = t; idx < NT*C; idx += 256){
    int ln = idx / C, c = idx - ln*C;
    nodemax[(size_t)(n0+ln)*C + c] = __int_as_float(nm[ln*CS + c]);
  }
  for (int p = 0; p < NP; ++p){
    __syncthreads();
    #pragma unroll
    for (int i = 0; i < 4; ++i) red[el][grp*4 + i] = sv[p][i];
    __syncthreads();
    if (t < 64){
      float a = 0.f;
      for (int e2 = 0; e2 < 16; ++e2) a += red[e2][t];
      statp[(size_t)blockIdx.x*2*C + p*64 + t] = a;
    }
    __syncthreads();
    #pragma unroll
    for (int i = 0; i < 4; ++i) red[el][grp*4 + i] = qv[p][i];
    __syncthreads();
    if (t < 64){
      float a = 0.f;
      for (int e2 = 0; e2 < 16; ++e2) a += red[e2][t];
      statp[(size_t)blockIdx.x*2*C + C + p*64 + t] = a;
    }
  }
}

// ======== PROVEN f32 kernels (fallback path) ========

template<int CIN, int C, int MODE>
__launch_bounds__(256)
__global__ void kstats1(const float* __restrict__ W1, const float* __restrict__ b1,
                        const float* __restrict__ in0, const float* __restrict__ posf,
                        const float* __restrict__ featf, const int* __restrict__ src,
                        const int* __restrict__ dst, int E, float* __restrict__ statp){
  constexpr int NP = C / 64;
  constexpr int CP = CIN / 2;
  __shared__ float A1[32][CIN + 1];
  __shared__ int Si[32], Sj[32];
  __shared__ float red[16][64];
  int t = threadIdx.x, el = t & 15, grp = t >> 4;
  float sv[NP][4], qv[NP][4];
  #pragma unroll
  for (int p = 0; p < NP; ++p)
    #pragma unroll
    for (int i = 0; i < 4; ++i){ sv[p][i] = 0.f; qv[p][i] = 0.f; }

  int ntiles = (E + 31) / 32;
  for (int tt = blockIdx.x; tt < ntiles; tt += gridDim.x){
    int tile = tt * 32;
    int nrows = E - tile; if (nrows > 32) nrows = 32;
    __syncthreads();
    if (t < 32){
      if (t < nrows){ Si[t] = dst[tile + t]; Sj[t] = src[tile + t]; }
      else { Si[t] = 0; Sj[t] = 0; }
    }
    __syncthreads();
    for (int idx = t; idx < 32*CIN; idx += 256){
      int r = idx / CIN, k = idx - r*CIN;
      float v = 0.f;
      if (r < nrows){
        int i = Si[r], j = Sj[r];
        v = (k < CP) ? in0[(size_t)i*CP + k]
                     : in0[(size_t)j*CP + (k-CP)] - in0[(size_t)i*CP + (k-CP)];
      }
      A1[r][k] = v;
    }
    __syncthreads();
    float acc[NP][2][4];
    #pragma unroll
    for (int p = 0; p < NP; ++p)
      #pragma unroll
      for (int i = 0; i < 4; ++i){ float b = b1[p*64 + grp*4 + i]; acc[p][0][i] = b; acc[p][1][i] = b; }
    #pragma unroll 2
    for (int k = 0; k < CIN; ++k){
      float a0 = A1[el][k], a1 = A1[el+16][k];
      #pragma unroll
      for (int p = 0; p < NP; ++p){
        float4 w = *reinterpret_cast<const float4*>(&W1[(size_t)k*C + p*64 + grp*4]);
        acc[p][0][0] = fmaf(a0, w.x, acc[p][0][0]); acc[p][0][1] = fmaf(a0, w.y, acc[p][0][1]);
        acc[p][0][2] = fmaf(a0, w.z, acc[p][0][2]); acc[p][0][3] = fmaf(a0, w.w, acc[p][0][3]);
        acc[p][1][0] = fmaf(a1, w.x, acc[p][1][0]); acc[p][1][1] = fmaf(a1, w.y, acc[p][1][1]);
        acc[p][1][2] = fmaf(a1, w.z, acc[p][1][2]); acc[p][1][3] = fmaf(a1, w.w, acc[p][1][3]);
      }
    }
    #pragma unroll
    for (int p = 0; p < NP; ++p)
      #pragma unroll
      for (int q = 0; q < 2; ++q){
        int row = el + q*16;
        if (row < nrows){
          #pragma unroll
          for (int i = 0; i < 4; ++i){
            float v = fmaxf(acc[p][q][i], 0.f);
            sv[p][i] += v; qv[p][i] += v*v;
          }
        }
      }
  }
  for (int p = 0; p < NP; ++p){
    __syncthreads();
    #pragma unroll
    for (int i = 0; i < 4; ++i) red[el][grp*4 + i] = sv[p][i];
    __syncthreads();
    if (t < 64){
      float a = 0.f;
      for (int e2 = 0; e2 < 16; ++e2) a += red[e2][t];
      statp[(size_t)blockIdx.x*2*C + p*64 + t] = a;
    }
    __syncthreads();
    #pragma unroll
    for (int i = 0; i < 4; ++i) red[el][grp*4 + i] = qv[p][i];
    __syncthreads();
    if (t < 64){
      float a = 0.f;
      for (int e2 = 0; e2 < 16; ++e2) a += red[e2][t];
      statp[(size_t)blockIdx.x*2*C + C + p*64 + t] = a;
    }
  }
}

template<int CIN, int C, int TE>
__launch_bounds__(256)
__global__ void kfused(const float* __restrict__ W1, const float* __restrict__ b1,
                       const float* __restrict__ W2, const float* __restrict__ b2,
                       const float* __restrict__ sc1, const float* __restrict__ sh1,
                       const float* __restrict__ in0,
                       const int* __restrict__ src, const int* __restrict__ dst,
                       const int* __restrict__ eidx, const int* __restrict__ rp,
                       float* __restrict__ nodemax, float* __restrict__ statp)
{
  constexpr int NT  = 16;
  constexpr int EPL = TE / 16;
  constexpr int NP  = C / 64;
  constexpr int CP  = CIN / 2;
  __shared__ float A1[TE][CIN + 1];
  __shared__ float H1[TE][C + 1];
  __shared__ float NM[NT][C];
  __shared__ float red[16][64];
  __shared__ int Si[TE], Sj[TE];
  float* H2 = &A1[0][0];

  int t = threadIdx.x, el = t & 15, grp = t >> 4;
  int n0 = blockIdx.x * NT;
  int e_begin = rp[n0];
  int e_end   = rp[n0 + NT];

  for (int i = t; i < NT*C; i += 256) (&NM[0][0])[i] = -INFINITY;

  float s2[NP][4], q2[NP][4];
  #pragma unroll
  for (int p = 0; p < NP; ++p)
    #pragma unroll
    for (int i = 0; i < 4; ++i){ s2[p][i] = 0.f; q2[p][i] = 0.f; }

  for (int tile = e_begin; tile < e_end; tile += TE){
    int nrows = e_end - tile; if (nrows > TE) nrows = TE;
    __syncthreads();
    if (t < TE){
      if (t < nrows){ int e = eidx[tile + t]; Si[t] = dst[e]; Sj[t] = src[e]; }
      else { Si[t] = 0; Sj[t] = 0; }
    }
    __syncthreads();
    for (int idx = t; idx < TE*CIN; idx += 256){
      int r = idx / CIN, k = idx - r*CIN;
      float v = 0.f;
      if (r < nrows){
        int i = Si[r], j = Sj[r];
        v = (k < CP) ? in0[(size_t)i*CP + k]
                     : in0[(size_t)j*CP + (k-CP)] - in0[(size_t)i*CP + (k-CP)];
      }
      A1[r][k] = v;
    }
    __syncthreads();
    {
      float acc[NP][EPL][4];
      #pragma unroll
      for (int p = 0; p < NP; ++p)
        #pragma unroll
        for (int i = 0; i < 4; ++i){
          float b = b1[p*64 + grp*4 + i];
          #pragma unroll
          for (int q = 0; q < EPL; ++q) acc[p][q][i] = b;
        }
      #pragma unroll 2
      for (int k = 0; k < CIN; ++k){
        float a[EPL];
        #pragma unroll
        for (int q = 0; q < EPL; ++q) a[q] = A1[el + q*16][k];
        #pragma unroll
        for (int p = 0; p < NP; ++p){
          float4 w = *reinterpret_cast<const float4*>(&W1[(size_t)k*C + p*64 + grp*4]);
          #pragma unroll
          for (int q = 0; q < EPL; ++q){
            acc[p][q][0] = fmaf(a[q], w.x, acc[p][q][0]);
            acc[p][q][1] = fmaf(a[q], w.y, acc[p][q][1]);
            acc[p][q][2] = fmaf(a[q], w.z, acc[p][q][2]);
            acc[p][q][3] = fmaf(a[q], w.w, acc[p][q][3]);
          }
        }
      }
      #pragma unroll
      for (int p = 0; p < NP; ++p)
        #pragma unroll
        for (int q = 0; q < EPL; ++q){
          int row = el + q*16;
          if (row < nrows){
            int c = p*64 + grp*4;
            #pragma unroll
            for (int i = 0; i < 4; ++i)
              H1[row][c+i] = fmaxf(acc[p][q][i], 0.f) * sc1[c+i] + sh1[c+i];
          }
        }
    }
    __syncthreads();
    {
      float acc[NP][EPL][4];
      #pragma unroll
      for (int p = 0; p < NP; ++p)
        #pragma unroll
        for (int i = 0; i < 4; ++i){
          float b = b2[p*64 + grp*4 + i];
          #pragma unroll
          for (int q = 0; q < EPL; ++q) acc[p][q][i] = b;
        }
      #pragma unroll 2
      for (int k = 0; k < C; ++k){
        float a[EPL];
        #pragma unroll
        for (int q = 0; q < EPL; ++q) a[q] = H1[el + q*16][k];
        #pragma unroll
        for (int p = 0; p < NP; ++p){
          float4 w = *reinterpret_cast<const float4*>(&W2[(size_t)k*C + p*64 + grp*4]);
          #pragma unroll
          for (int q = 0; q < EPL; ++q){
            acc[p][q][0] = fmaf(a[q], w.x, acc[p][q][0]);
            acc[p][q][1] = fmaf(a[q], w.y, acc[p][q][1]);
            acc[p][q][2] = fmaf(a[q], w.z, acc[p][q][2]);
            acc[p][q][3] = fmaf(a[q], w.w, acc[p][q][3]);
          }
        }
      }
      #pragma unroll
      for (int p = 0; p < NP; ++p)
        #pragma unroll
        for (int q = 0; q < EPL; ++q){
          int row = el + q*16;
          if (row < nrows){
            int c = p*64 + grp*4;
            #pragma unroll
            for (int i = 0; i < 4; ++i){
              float v = fmaxf(acc[p][q][i], 0.f);
              s2[p][i] += v; q2[p][i] += v*v;
              H2[row*(C+1) + c + i] = v;
            }
          }
        }
    }
    __syncthreads();
    for (int idx = t; idx < NT*C; idx += 256){
      int ln = idx / C, c = idx - ln*C;
      int n = n0 + ln;
      int lo = rp[n];   if (lo < tile) lo = tile;
      int hi = rp[n+1]; if (hi > tile + nrows) hi = tile + nrows;
      lo -= tile; hi -= tile;
      if (lo < hi){
        float m = NM[ln][c];
        for (int r = lo; r < hi; ++r) m = fmaxf(m, H2[r*(C+1) + c]);
        NM[ln][c] = m;
      }
    }
  }
  __syncthreads();
  for (int idx = t; idx < NT*C; idx += 256){
    int ln = idx / C, c = idx - ln*C;
    nodemax[(size_t)(n0+ln)*C + c] = NM[ln][c];
  }
  for (int p = 0; p < NP; ++p){
    __syncthreads();
    #pragma unroll
    for (int i = 0; i < 4; ++i) red[el][grp*4 + i] = s2[p][i];
    __syncthreads();
    if (t < 64){
      float a = 0.f;
      for (int e2 = 0; e2 < 16; ++e2) a += red[e2][t];
      statp[(size_t)blockIdx.x*2*C + p*64 + t] = a;
    }
    __syncthreads();
    #pragma unroll
    for (int i = 0; i < 4; ++i) red[el][grp*4 + i] = q2[p][i];
    __syncthreads();
    if (t < 64){
      float a = 0.f;
      for (int e2 = 0; e2 < 16; ++e2) a += red[e2][t];
      statp[(size_t)blockIdx.x*2*C + C + p*64 + t] = a;
    }
  }
}

// ---------------- stats reduce + BN finalize ----------------
__global__ void kstatred(const float* __restrict__ statp, int nblk, int C,
                         float* __restrict__ gs, float* __restrict__ gq){
  int c = blockIdx.x;
  float s = 0.f, q = 0.f;
  for (int b = threadIdx.x; b < nblk; b += 256){
    s += statp[(size_t)b*2*C + c];
    q += statp[(size_t)b*2*C + C + c];
  }
  __shared__ float ls[256], lq[256];
  ls[threadIdx.x] = s; lq[threadIdx.x] = q;
  __syncthreads();
  for (int o = 128; o; o >>= 1){
    if (threadIdx.x < o){ ls[threadIdx.x] += ls[threadIdx.x+o]; lq[threadIdx.x] += lq[threadIdx.x+o]; }
    __syncthreads();
  }
  if (threadIdx.x == 0){ gs[c] = ls[0]; gq[c] = lq[0]; }
}
__global__ void finalize_bn(const float* __restrict__ gs, const float* __restrict__ gq,
                            const float* __restrict__ g, const float* __restrict__ be,
                            float invR, float* __restrict__ sc, float* __restrict__ sh){
  int c = threadIdx.x;
  float m  = gs[c] * invR;
  float va = gq[c] * invR - m*m;
  float s  = g[c] * rsqrtf(va + 1e-5f);
  sc[c] = s;
  sh[c] = be[c] - m*s;
}

// ---------------- BN affine on node maxima ----------------
template<int C>
__global__ void kaffine(const float* __restrict__ nodemax, const int* __restrict__ rp,
                        const float* __restrict__ sc, const float* __restrict__ sh,
                        float* __restrict__ xo, int Nn){
  int i = blockIdx.x*256 + threadIdx.x;
  if (i >= Nn*C) return;
  int n = i / C, c = i - n*C;
  float v = 0.f;
  if (rp[n+1] > rp[n]) v = nodemax[i] * sc[c] + sh[c];
  xo[i] = v;
}

// ---------------- per-graph segment max of x123 (two-phase parallel) ----------------
__global__ void kxg_part(const float* __restrict__ x1, const float* __restrict__ x2,
                         const float* __restrict__ x3, const int* __restrict__ gptr,
                         float* __restrict__ xgpart){
  int g = blockIdx.x, ch = blockIdx.y;
  int t = threadIdx.x;
  int s = gptr[g], e = gptr[g+1];
  int len = e - s, per = (len + 31) / 32;
  int n0 = s + ch*per, n1 = n0 + per; if (n1 > e) n1 = e;
  float mx0 = -INFINITY, mx1 = -INFINITY;
  int c0 = t, c1 = t + 256;
  for (int n = n0; n < n1; ++n){
    float v0 = (c0 < 64)  ? x1[(size_t)n*64  + c0]
             : (c0 < 192) ? x2[(size_t)n*128 + (c0 - 64)]
                          : x3[(size_t)n*256 + (c0 - 192)];
    mx0 = fmaxf(mx0, v0);
    if (c1 < 448){
      float v1 = x3[(size_t)n*256 + (c1 - 192)];
      mx1 = fmaxf(mx1, v1);
    }
  }
  xgpart[(size_t)(g*32 + ch)*448 + c0] = mx0;
  if (c1 < 448) xgpart[(size_t)(g*32 + ch)*448 + c1] = mx1;
}
__global__ void kxg_red(const float* __restrict__ xgpart, const int* __restrict__ gptr,
                        float* __restrict__ xg){
  int g = blockIdx.x;
  int c = blockIdx.y * 256 + threadIdx.x;
  if (c >= 448) return;
  float mx = -INFINITY;
  for (int ch = 0; ch < 32; ++ch)
    mx = fmaxf(mx, xgpart[(size_t)(g*32 + ch)*448 + c]);
  xg[g*448 + c] = (gptr[g+1] > gptr[g] && !__builtin_isinf(mx)) ? mx : 0.f;
}

// ---------------- m1 ----------------
__launch_bounds__(256)
__global__ void km1(const float* __restrict__ Wf, const float* __restrict__ bias,
                    const float* __restrict__ x1, const float* __restrict__ x2,
                    const float* __restrict__ x3, float* __restrict__ x4p,
                    float* __restrict__ statp, int Nn){
  __shared__ float A[16][449];
  __shared__ float red[16][64];
  int t = threadIdx.x, el = t & 15, grp = t >> 4;
  int r0 = blockIdx.x * 16;
  for (int idx = t; idx < 16*448; idx += 256){
    int r = idx / 448, k = idx - r*448;
    int rr = r0 + r;
    float v = 0.f;
    if (rr < Nn)
      v = (k < 64)  ? x1[(size_t)rr*64  + k]
        : (k < 192) ? x2[(size_t)rr*128 + (k - 64)]
                    : x3[(size_t)rr*256 + (k - 192)];
    A[r][k] = v;
  }
  __syncthreads();
  float sv[4][4], qv[4][4];
  float acc[4][4];
  #pragma unroll
  for (int p = 0; p < 4; ++p)
    #pragma unroll
    for (int i = 0; i < 4; ++i){
      sv[p][i] = 0.f; qv[p][i] = 0.f;
      acc[p][i] = bias[p*64 + grp*4 + i];
    }
  #pragma unroll 2
  for (int k = 0; k < 448; ++k){
    float a = A[el][k];
    #pragma unroll
    for (int p = 0; p < 4; ++p){
      float4 w = *reinterpret_cast<const float4*>(&Wf[(size_t)k*256 + p*64 + grp*4]);
      acc[p][0] = fmaf(a, w.x, acc[p][0]); acc[p][1] = fmaf(a, w.y, acc[p][1]);
      acc[p][2] = fmaf(a, w.z, acc[p][2]); acc[p][3] = fmaf(a, w.w, acc[p][3]);
    }
  }
  int rr = r0 + el;
  #pragma unroll
  for (int p = 0; p < 4; ++p){
    if (rr < Nn){
      int c = p*64 + grp*4;
      float v0 = fmaxf(acc[p][0],0.f), v1 = fmaxf(acc[p][1],0.f);
      float v2 = fmaxf(acc[p][2],0.f), v3 = fmaxf(acc[p][3],0.f);
      sv[p][0]=v0; sv[p][1]=v1; sv[p][2]=v2; sv[p][3]=v3;
      qv[p][0]=v0*v0; qv[p][1]=v1*v1; qv[p][2]=v2*v2; qv[p][3]=v3*v3;
      float4 o; o.x=v0; o.y=v1; o.z=v2; o.w=v3;
      *reinterpret_cast<float4*>(&x4p[(size_t)rr*256 + c]) = o;
    }
  }
  for (int p = 0; p < 4; ++p){
    __syncthreads();
    #pragma unroll
    for (int i = 0; i < 4; ++i) red[el][grp*4 + i] = sv[p][i];
    __syncthreads();
    if (t < 64){
      float a = 0.f;
      for (int e2 = 0; e2 < 16; ++e2) a += red[e2][t];
      statp[(size_t)blockIdx.x*512 + p*64 + t] = a;
    }
    __syncthreads();
    #pragma unroll
    for (int i = 0; i < 4; ++i) red[el][grp*4 + i] = qv[p][i];
    __syncthreads();
    if (t < 64){
      float a = 0.f;
      for (int e2 = 0; e2 < 16; ++e2) a += red[e2][t];
      statp[(size_t)blockIdx.x*512 + 256 + p*64 + t] = a;
    }
  }
}

// ---------------- m2 + bn8 ----------------
__global__ void m2_mlp(const float* __restrict__ xg, const float* __restrict__ Wf,
                       const float* __restrict__ b, float* __restrict__ u_pre){
  __shared__ float row[448];
  int g = blockIdx.x, t = threadIdx.x;
  for (int k = t; k < 448; k += 256) row[k] = xg[g*448 + k];
  __syncthreads();
  float acc = b[t];
  #pragma unroll 4
  for (int k = 0; k < 448; ++k) acc = fmaf(row[k], Wf[(size_t)k*256 + t], acc);
  u_pre[g*256 + t] = fmaxf(acc, 0.f);
}
__global__ void bn8(const float* __restrict__ u_pre, const float* __restrict__ g,
                    const float* __restrict__ be, float* __restrict__ u_bn){
  int c = threadIdx.x;
  float s = 0.f, q = 0.f;
  for (int r = 0; r < 8; ++r){ float v = u_pre[r*256 + c]; s += v; q += v*v; }
  float m  = s * 0.125f;
  float va = q * 0.125f - m*m;
  float scl = g[c] * rsqrtf(va + 1e-5f);
  float sht = be[c] - m*scl;
  for (int r = 0; r < 8; ++r) u_bn[r*256 + c] = u_pre[r*256 + c]*scl + sht;
}

// ---------------- einsum ----------------
__global__ void keinsum(const float* __restrict__ x4p, const float* __restrict__ sc4,
                        const float* __restrict__ sh4, const float* __restrict__ hmf,
                        const int* __restrict__ gptr, float* __restrict__ x6part){
  int g = blockIdx.x, s32 = blockIdx.y, c = threadIdx.x;
  int s = gptr[g], e = gptr[g+1];
  int len = e - s;
  int per = (len + 31) / 32;
  int n0 = s + s32*per;
  int n1 = n0 + per; if (n1 > e) n1 = e;
  float scl = sc4[c], shf = sh4[c];
  float acc[24];
  #pragma unroll
  for (int i = 0; i < 24; ++i) acc[i] = 0.f;
  __shared__ float hrow[16][24];
  for (int nb = n0; nb < n1; nb += 16){
    int cntn = n1 - nb; if (cntn > 16) cntn = 16;
    __syncthreads();
    for (int i = threadIdx.x; i < cntn*24; i += 256)
      hrow[i/24][i%24] = hmf[(size_t)nb*24 + i];
    __syncthreads();
    for (int j = 0; j < cntn; ++j){
      float a = x4p[(size_t)(nb+j)*256 + c] * scl + shf;
      #pragma unroll
      for (int i = 0; i < 24; ++i) acc[i] = fmaf(a, hrow[j][i], acc[i]);
    }
  }
  #pragma unroll
  for (int i = 0; i < 24; ++i)
    x6part[((size_t)(g*32 + s32)*24 + i)*256 + c] = acc[i];
}
__global__ void keired(const float* __restrict__ x6part, float* __restrict__ x6p){
  int gk = blockIdx.x;
  int g = gk / 24, k = gk - g*24, c = threadIdx.x;
  float a = 0.f;
  for (int s32 = 0; s32 < 32; ++s32)
    a += x6part[((size_t)(g*32 + s32)*24 + k)*256 + c];
  x6p[(size_t)gk*256 + c] = a;
}

// ---------------- final linear + relu + BN (f32 output) ----------------
__global__ void lin_relu_k(const float* __restrict__ x6p, const float* __restrict__ u_bn,
                           const float* __restrict__ hs, const float* __restrict__ Wf,
                           const float* __restrict__ b, float* __restrict__ x7p){
  __shared__ float row[512];
  int r = blockIdx.x, t = threadIdx.x;
  int g = r / 24, kk = r - g*24;
  row[t]       = x6p[(size_t)r*256 + t];
  row[256 + t] = u_bn[g*256 + t] * hs[g*24 + kk];
  __syncthreads();
  float acc = b[t];
  #pragma unroll 4
  for (int k = 0; k < 512; ++k) acc = fmaf(row[k], Wf[(size_t)k*256 + t], acc);
  x7p[(size_t)r*256 + t] = fmaxf(acc, 0.f);
}
__global__ void final_bn_k(const float* __restrict__ x7p, const float* __restrict__ g,
                           const float* __restrict__ be, float* __restrict__ out){
  int c = threadIdx.x;
  float s = 0.f, q = 0.f;
  for (int r = 0; r < 192; ++r){ float v = x7p[(size_t)r*256 + c]; s += v; q += v*v; }
  const float inv = 1.f / 192.f;
  float m  = s * inv;
  float va = q * inv - m*m;
  float scl = g[c] * rsqrtf(va + 1e-5f);
  float sht = be[c] - m*scl;
  for (int r = 0; r < 192; ++r)
    out[(size_t)r*256 + c] = x7p[(size_t)r*256 + c]*scl + sht;
}

__global__ void kerr(float* out, float code){ if (threadIdx.x == 0) out[0] = code; }

extern "C" void kernel_launch(void* const* d_in, const int* in_sizes, int n_in,
                              void* d_out, int out_size, void* d_ws, size_t ws_size,
                              hipStream_t stream)
{
  const int N = in_sizes[0] / 3;
  const int E = in_sizes[3] / 2;
  float* outf = (float*)d_out;

  // ---- host-side input-map verification ----
  {
    const int co_[3] = {64,128,256};
    int exp41[41];
    exp41[0]=N*3; exp41[1]=N*61; exp41[2]=N*24; exp41[3]=2*E; exp41[4]=N;
    int idx=5;
    for (int i=0;i<3;++i){
      int ci = (i==0)?128:(i==1)?128:256;
      exp41[idx++]=ci*co_[i]; exp41[idx++]=co_[i]; exp41[idx++]=co_[i]; exp41[idx++]=co_[i];
      exp41[idx++]=co_[i]*co_[i]; exp41[idx++]=co_[i]; exp41[idx++]=co_[i]; exp41[idx++]=co_[i];
    }
    for (int r=0;r<2;++r){ exp41[idx++]=448*256; exp41[idx++]=256; exp41[idx++]=256; exp41[idx++]=256; }
    exp41[idx++]=512*256; exp41[idx++]=256; exp41[idx++]=256; exp41[idx++]=256;
    int bad = -1;
    if (n_in != 41) bad = 99;
    else for (int i=0;i<41;++i) if (in_sizes[i] != exp41[i]){ bad = i; break; }
    if (bad >= 0){
      kerr<<<1, 64, 0, stream>>>(outf, 100000.f + (float)bad);
      return;
    }
  }

  const int*  tei   = (const int*)d_in[3];
  const int*  batch = (const int*)d_in[4];
  const int*  srcp  = tei;
  const int*  dstp  = tei + E;

  char* base = (char*)d_ws;
  size_t off = 0;
  auto alloc = [&](size_t bytes) -> void* {
    void* p = base + off;
    off = (off + bytes + 255) & ~((size_t)255);
    return p;
  };

  int* flag = (int*)alloc(256);

  float* posf  = (float*)alloc((size_t)N*3*4);
  float* featf = (float*)alloc((size_t)N*61*4);
  float* hmf   = (float*)alloc((size_t)N*24*4);
  float* x0f   = (float*)alloc((size_t)N*64*4);
  float* w1f[3]; float* w2f[3];
  float* b1f[3]; float* g1f[3]; float* be1f[3];
  float* b2ff[3]; float* g2f[3]; float* be2f[3];
  float* s1a[3]; float* h1a[3]; float* s2a[3]; float* h2a[3];
  const int cin1[3] = {128, 128, 256};
  const int co[3]   = {64, 128, 256};
  for (int i = 0; i < 3; ++i){
    w1f[i]  = (float*)alloc((size_t)cin1[i]*co[i]*4);
    w2f[i]  = (float*)alloc((size_t)co[i]*co[i]*4);
    b1f[i]  = (float*)alloc(co[i]*4);
    g1f[i]  = (float*)alloc(co[i]*4);
    be1f[i] = (float*)alloc(co[i]*4);
    b2ff[i] = (float*)alloc(co[i]*4);
    g2f[i]  = (float*)alloc(co[i]*4);
    be2f[i] = (float*)alloc(co[i]*4);
    s1a[i]  = (float*)alloc(co[i]*4);
    h1a[i]  = (float*)alloc(co[i]*4);
    s2a[i]  = (float*)alloc(co[i]*4);
    h2a[i]  = (float*)alloc(co[i]*4);
  }
  float* w1df = (float*)alloc((size_t)128*256*4);   // W1top - W1bot (max size)
  float* m1wf = (float*)alloc(448*256*4);
  float* m1bf = (float*)alloc(256*4);
  float* m1gf = (float*)alloc(256*4);
  float* m1bef= (float*)alloc(256*4);
  float* m2wf = (float*)alloc(448*256*4);
  float* m2bf = (float*)alloc(256*4);
  float* m2gf = (float*)alloc(256*4);
  float* m2bef= (float*)alloc(256*4);
  float* linwf= (float*)alloc(512*256*4);
  float* linbf= (float*)alloc(256*4);
  float* bngf = (float*)alloc(256*4);
  float* bnbf = (float*)alloc(256*4);

  float* x1 = (float*)alloc((size_t)N*64*4);
  float* x2 = (float*)alloc((size_t)N*128*4);
  float* nodemax = (float*)alloc((size_t)N*256*4);
  float* x4p = nodemax;                          // alias: nodemax dead before km1

  float* statp = (float*)alloc((size_t)3200*512*4);
  int* part = (int*)alloc((size_t)NB_SORT*N*4);
  int* eidx = (int*)alloc((size_t)E*4);
  int* rp   = (int*)alloc((size_t)(N+1)*4);
  int* cnt  = (int*)alloc((size_t)N*4);
  int* gptr = (int*)alloc(16*4);

  float* gs  = (float*)alloc(256*4);
  float* gq  = (float*)alloc(256*4);
  float* sc4 = (float*)alloc(256*4); float* sh4 = (float*)alloc(256*4);
  float* hs  = (float*)alloc(192*4);

  // ubuf: uu for all GCUs; x3 aliases it (x3 written only after GCU3 done)
  float* ubuf = (float*)alloc((size_t)N*256*4);
  float* x3 = ubuf;

  // vbuf: vv for all GCUs if it fits; post-GCU tail buffers always alias it
  const size_t tailFl = 1793536;                 // floats needed by tail buffers
  const size_t fastB  = (size_t)N*256*4;
  size_t off0 = off;
  int plan = (off0 + fastB + (1u<<20) <= ws_size) ? 1 : 0;
  float* vbuf = (float*)alloc(plan ? fastB : (tailFl*4 + 1024));
  float* x6part = vbuf;
  float* xgpart = vbuf + 1572864;
  float* x6p    = vbuf + 1687552;
  float* x7p    = vbuf + 1736704;
  float* u_pre  = vbuf + 1785856;
  float* u_bn   = vbuf + 1787904;
  float* xg     = vbuf + 1789952;
  (void)out_size;

  kdetect<<<1, 256, 0, stream>>>((const unsigned short*)d_in[0], flag);
  CTab tab;
  int ti = 0;
  auto add = [&](int idx, float* dstp_, int n){ tab.e[ti].s = d_in[idx]; tab.e[ti].d = dstp_; tab.e[ti].n = n; ++ti; };
  add(0, posf,  N*3);
  add(1, featf, N*61);
  add(2, hmf,   N*24);
  for (int i = 0; i < 3; ++i){
    int b0 = 5 + i*8;
    add(b0+0, w1f[i],  cin1[i]*co[i]);
    add(b0+1, b1f[i],  co[i]);
    add(b0+2, g1f[i],  co[i]);
    add(b0+3, be1f[i], co[i]);
    add(b0+4, w2f[i],  co[i]*co[i]);
    add(b0+5, b2ff[i], co[i]);
    add(b0+6, g2f[i],  co[i]);
    add(b0+7, be2f[i], co[i]);
  }
  add(29, m1wf, 448*256); add(30, m1bf, 256); add(31, m1gf, 256); add(32, m1bef, 256);
  add(33, m2wf, 448*256); add(34, m2bf, 256); add(35, m2gf, 256); add(36, m2bef, 256);
  add(37, linwf, 512*256); add(38, linbf, 256); add(39, bngf, 256); add(40, bnbf, 256);
  kconv<<<dim3(64, 39), 256, 0, stream>>>(tab, flag);

  kpack0<<<(N*64 + 255)/256, 256, 0, stream>>>(posf, featf, x0f, N);

  kgptr<<<1, 64, 0, stream>>>(batch, N, gptr);
  khs<<<8, 256, 0, stream>>>(hmf, gptr, hs);

  // ---- parallel counting sort of edges by dst ----
  const int gridN = (N + 255)/256;
  khist<<<NB_SORT, 256, 0, stream>>>(dstp, E, N, part);
  kcnt<<<gridN, 256, 0, stream>>>(part, N, cnt);
  kscan<<<1, 256, 0, stream>>>(cnt, N, rp);
  kpre<<<gridN, 256, 0, stream>>>(part, N);
  kscatter<<<NB_SORT, 256, 0, stream>>>(dstp, E, N, part, rp, eidx);

  const int NBKF = N / 16;
  const int nblk16 = (N + 15) / 16;
  const float invE = 1.f / (float)E;

  if (plan){
    float* uu = ubuf;
    float* vv = vbuf;
    // ---- GCU1: CP=64, C=64 ----
    kwd<<<(64*64 + 255)/256, 256, 0, stream>>>(w1f[0], w1df, 64*64);
    knode_f32<64,64><<<nblk16, 256, 0, stream>>>(w1df, w1f[0] + 64*64, b1f[0], x0f, uu, vv, N);
    kh1stats<64><<<1024, 256, 0, stream>>>(uu, vv, srcp, dstp, eidx, E, statp);
    kstatred<<<64, 256, 0, stream>>>(statp, 1024, 64, gs, gq);
    finalize_bn<<<1, 64, 0, stream>>>(gs, gq, g1f[0], be1f[0], invE, s1a[0], h1a[0]);
    kfused_g2<64><<<NBKF, 256, 0, stream>>>(w2f[0], b2ff[0], s1a[0], h1a[0],
        uu, vv, srcp, dstp, eidx, rp, N, nodemax, statp);
    kstatred<<<64, 256, 0, stream>>>(statp, NBKF, 64, gs, gq);
    finalize_bn<<<1, 64, 0, stream>>>(gs, gq, g2f[0], be2f[0], invE, s2a[0], h2a[0]);
    kaffine<64><<<(N*64 + 255)/256, 256, 0, stream>>>(nodemax, rp, s2a[0], h2a[0], x1, N);
    // ---- GCU2: CP=64, C=128 ----
    kwd<<<(64*128 + 255)/256, 256, 0, stream>>>(w1f[1], w1df, 64*128);
    knode_f32<64,128><<<nblk16, 256, 0, stream>>>(w1df, w1f[1] + 64*128, b1f[1], x1, uu, vv, N);
    kh1stats<128><<<1024, 256, 0, stream>>>(uu, vv, srcp, dstp, eidx, E, statp);
    kstatred<<<128, 256, 0, stream>>>(statp, 1024, 128, gs, gq);
    finalize_bn<<<1, 128, 0, stream>>>(gs, gq, g1f[1], be1f[1], invE, s1a[1], h1a[1]);
    kfused_g2<128><<<NBKF, 256, 0, stream>>>(w2f[1], b2ff[1], s1a[1], h1a[1],
        uu, vv, srcp, dstp, eidx, rp, N, nodemax, statp);
    kstatred<<<128, 256, 0, stream>>>(statp, NBKF, 128, gs, gq);
    finalize_bn<<<1, 128, 0, stream>>>(gs, gq, g2f[1], be2f[1], invE, s2a[1], h2a[1]);
    kaffine<128><<<(N*128 + 255)/256, 256, 0, stream>>>(nodemax, rp, s2a[1], h2a[1], x2, N);
    // ---- GCU3: CP=128, C=256 ----
    kwd<<<(128*256 + 255)/256, 256, 0, stream>>>(w1f[2], w1df, 128*256);
    knode_f32<128,256><<<nblk16, 256, 0, stream>>>(w1df, w1f[2] + 128*256, b1f[2], x2, uu, vv, N);
    kh1stats<256><<<1024, 256, 0, stream>>>(uu, vv, srcp, dstp, eidx, E, statp);
    kstatred<<<256, 256, 0, stream>>>(statp, 1024, 256, gs, gq);
    finalize_bn<<<1, 256, 0, stream>>>(gs, gq, g1f[2], be1f[2], invE, s1a[2], h1a[2]);
    kfused_g2<256><<<NBKF, 256, 0, stream>>>(w2f[2], b2ff[2], s1a[2], h1a[2],
        uu, vv, srcp, dstp, eidx, rp, N, nodemax, statp);
    kstatred<<<256, 256, 0, stream>>>(statp, NBKF, 256, gs, gq);
    finalize_bn<<<1, 256, 0, stream>>>(gs, gq, g2f[2], be2f[2], invE, s2a[2], h2a[2]);
    kaffine<256><<<(N*256 + 255)/256, 256, 0, stream>>>(nodemax, rp, s2a[2], h2a[2], x3, N);
  } else {
    // ---- fallback: known-good R10 f32 path ----
    const int NBK1 = 1024;
    kstats1<128,64,0><<<NBK1, 256, 0, stream>>>(w1f[0], b1f[0], x0f, nullptr, nullptr,
        srcp, dstp, E, statp);
    kstatred<<<64, 256, 0, stream>>>(statp, NBK1, 64, gs, gq);
    finalize_bn<<<1, 64, 0, stream>>>(gs, gq, g1f[0], be1f[0], invE, s1a[0], h1a[0]);
    kfused<128,64,32><<<NBKF, 256, 0, stream>>>(w1f[0], b1f[0], w2f[0], b2ff[0],
        s1a[0], h1a[0], x0f, srcp, dstp, eidx, rp, nodemax, statp);
    kstatred<<<64, 256, 0, stream>>>(statp, NBKF, 64, gs, gq);
    finalize_bn<<<1, 64, 0, stream>>>(gs, gq, g2f[0], be2f[0], invE, s2a[0], h2a[0]);
    kaffine<64><<<(N*64 + 255)/256, 256, 0, stream>>>(nodemax, rp, s2a[0], h2a[0], x1, N);

    kstats1<128,128,0><<<NBK1, 256, 0, stream>>>(w1f[1], b1f[1], x1, nullptr, nullptr,
        srcp, dstp, E, statp);
    kstatred<<<128, 256, 0, stream>>>(statp, NBK1, 128, gs, gq);
    finalize_bn<<<1, 128, 0, stream>>>(gs, gq, g1f[1], be1f[1], invE, s1a[1], h1a[1]);
    kfused<128,128,32><<<NBKF, 256, 0, stream>>>(w1f[1], b1f[1], w2f[1], b2ff[1],
        s1a[1], h1a[1], x1, srcp, dstp, eidx, rp, nodemax, statp);
    kstatred<<<128, 256, 0, stream>>>(statp, NBKF, 128, gs, gq);
    finalize_bn<<<1, 128, 0, stream>>>(gs, gq, g2f[1], be2f[1], invE, s2a[1], h2a[1]);
    kaffine<128><<<(N*128 + 255)/256, 256, 0, stream>>>(nodemax, rp, s2a[1], h2a[1], x2, N);

    kstats1<256,256,0><<<NBK1, 256, 0, stream>>>(w1f[2], b1f[2], x2, nullptr, nullptr,
        srcp, dstp, E, statp);
    kstatred<<<256, 256, 0, stream>>>(statp, NBK1, 256, gs, gq);
    finalize_bn<<<1, 256, 0, stream>>>(gs, gq, g1f[2], be1f[2], invE, s1a[2], h1a[2]);
    kfused<256,256,16><<<NBKF, 256, 0, stream>>>(w1f[2], b1f[2], w2f[2], b2ff[2],
        s1a[2], h1a[2], x2, srcp, dstp, eidx, rp, nodemax, statp);
    kstatred<<<256, 256, 0, stream>>>(statp, NBKF, 256, gs, gq);
    finalize_bn<<<1, 256, 0, stream>>>(gs, gq, g2f[2], be2f[2], invE, s2a[2], h2a[2]);
    kaffine<256><<<(N*256 + 255)/256, 256, 0, stream>>>(nodemax, rp, s2a[2], h2a[2], x3, N);
  }

  // graph pooling (parallel two-phase)
  kxg_part<<<dim3(8, 32), 256, 0, stream>>>(x1, x2, x3, gptr, xgpart);
  kxg_red<<<dim3(8, 2), 256, 0, stream>>>(xgpart, gptr, xg);

  km1<<<NBKF, 256, 0, stream>>>(m1wf, m1bf, x1, x2, x3, x4p, statp, N);
  kstatred<<<256, 256, 0, stream>>>(statp, NBKF, 256, gs, gq);
  finalize_bn<<<1, 256, 0, stream>>>(gs, gq, m1gf, m1bef, 1.f/(float)N, sc4, sh4);

  m2_mlp<<<8, 256, 0, stream>>>(xg, m2wf, m2bf, u_pre);
  bn8<<<1, 256, 0, stream>>>(u_pre, m2gf, m2bef, u_bn);

  keinsum<<<dim3(8, 32), 256, 0, stream>>>(x4p, sc4, sh4, hmf, gptr, x6part);
  keired<<<192, 256, 0, stream>>>(x6part, x6p);

  lin_relu_k<<<192, 256, 0, stream>>>(x6p, u_bn, hs, linwf, linbf, x7p);
  final_bn_k<<<1, 256, 0, stream>>>(x7p, bngf, bnbf, outf);
}

// Round 13
// 5654.605 us; speedup vs baseline: 1.2725x; 1.2725x over previous
//
#include <hip/hip_runtime.h>
#include <hip/hip_bf16.h>
#include <cstdint>

using bf16 = __hip_bfloat16;
#define DI __device__ __forceinline__

DI float b2f(bf16 v){ return __bfloat162float(v); }
DI float us2f(unsigned short u){ bf16 t; *reinterpret_cast<unsigned short*>(&t) = u; return __bfloat162float(t); }

// R23: R22 with the statp transcription bug fixed (R22 dropped "p*64" in
// kfused_g2's sumsq write -> BN2 variance garbage for C>64 -> absmax 3.74).
// Design = R20 (PASS 5.49ms) + nm stride C+1 padding, unroll 2.
// Identical arithmetic -> absmax 0.015625. Output FLOAT32.

// ---------------- dtype detection on pos (~N(0,1)) ----------------
__global__ void kdetect(const unsigned short* __restrict__ pos_u, int* __restrict__ flag){
  __shared__ int cE, cO;
  if (threadIdx.x == 0){ cE = 0; cO = 0; }
  __syncthreads();
  int pe = 0, po = 0;
  for (int i = threadIdx.x; i < 2048; i += 256){
    float ve = fabsf(us2f(pos_u[2*i]));
    float vo = fabsf(us2f(pos_u[2*i + 1]));
    if (ve > 1e-4f && ve < 50.f) pe++;
    if (vo > 1e-4f && vo < 50.f) po++;
  }
  atomicAdd(&cE, pe);
  atomicAdd(&cO, po);
  __syncthreads();
  if (threadIdx.x == 0)
    flag[0] = (2*cE < cO) ? 1 : 0;   // 1 => inputs are f32
}

// ---------------- normalize all float inputs to f32 ----------------
struct CEnt { const void* s; float* d; int n; };
struct CTab { CEnt e[39]; };
__global__ void kconv(CTab tab, const int* __restrict__ flag){
  CEnt en = tab.e[blockIdx.y];
  const bool isf32 = (flag[0] != 0);
  for (int i = blockIdx.x*256 + threadIdx.x; i < en.n; i += gridDim.x*256)
    en.d[i] = isf32 ? ((const float*)en.s)[i] : b2f(((const bf16*)en.s)[i]);
}

// ---------------- pack x_in = [pos | feat]  [N][64] ----------------
__global__ void kpack0(const float* __restrict__ posf, const float* __restrict__ featf,
                       float* __restrict__ x0, int Nn){
  int i = blockIdx.x*256 + threadIdx.x;
  if (i >= Nn*64) return;
  int n = i >> 6, c = i & 63;
  x0[i] = (c < 3) ? posf[(size_t)n*3 + c] : featf[(size_t)n*61 + (c-3)];
}

// ---------------- W1d = W1top - W1bot ----------------
__global__ void kwd(const float* __restrict__ W1, float* __restrict__ W1d, int CPC){
  int i = blockIdx.x*256 + threadIdx.x;
  if (i < CPC) W1d[i] = W1[i] - W1[CPC + i];
}

// ---------------- graph partition ----------------
__global__ void kgptr(const int* __restrict__ batch, int Nn, int* __restrict__ gptr){
  int g = threadIdx.x;
  if (g > 8) return;
  if (g == 8){ gptr[8] = Nn; return; }
  int lo = 0, hi = Nn;
  while (lo < hi){ int mid = (lo + hi) >> 1; if (batch[mid] < g) lo = mid + 1; else hi = mid; }
  gptr[g] = lo;
}

// ---------------- per-graph heatmap column sums ----------------
__global__ void khs(const float* __restrict__ hmf, const int* __restrict__ gptr,
                    float* __restrict__ hs){
  int g = blockIdx.x;
  int lane = threadIdx.x % 24, slice = threadIdx.x / 24;
  __shared__ float part[10][24];
  if (threadIdx.x < 240){
    int s = gptr[g], e = gptr[g+1];
    float acc = 0.f;
    for (int n = s + slice; n < e; n += 10) acc += hmf[(size_t)n*24 + lane];
    part[slice][lane] = acc;
  }
  __syncthreads();
  if (threadIdx.x < 24){
    float a = 0.f;
    for (int i = 0; i < 10; ++i) a += part[i][threadIdx.x];
    hs[g*24 + threadIdx.x] = a;
  }
}

// ---------------- parallel counting sort of edges by dst (64 blocks) ----------------
#define NB_SORT 64
#define SORT_BINS 8192
__global__ void khist(const int* __restrict__ dst, int E, int Nn, int* __restrict__ part){
  int b = blockIdx.x;
  int per = (E + NB_SORT - 1) / NB_SORT;
  int s = b*per, e_end = s + per; if (e_end > E) e_end = E;
  __shared__ int h[SORT_BINS];
  for (int base = 0; base < Nn; base += SORT_BINS){
    for (int i = threadIdx.x; i < SORT_BINS; i += 256) h[i] = 0;
    __syncthreads();
    for (int e = s + threadIdx.x; e < e_end; e += 256){
      int d = dst[e] - base;
      if (d >= 0 && d < SORT_BINS) atomicAdd(&h[d], 1);
    }
    __syncthreads();
    int lim = Nn - base; if (lim > SORT_BINS) lim = SORT_BINS;
    for (int i = threadIdx.x; i < lim; i += 256) part[(size_t)b*Nn + base + i] = h[i];
    __syncthreads();
  }
}
__global__ void kcnt(const int* __restrict__ part, int Nn, int* __restrict__ cnt){
  int n = blockIdx.x*256 + threadIdx.x; if (n >= Nn) return;
  int s = 0;
  for (int b = 0; b < NB_SORT; ++b) s += part[(size_t)b*Nn + n];
  cnt[n] = s;
}
__global__ void kpre(int* part, int Nn){
  int n = blockIdx.x*256 + threadIdx.x; if (n >= Nn) return;
  int run = 0;
  for (int b = 0; b < NB_SORT; ++b){
    int v = part[(size_t)b*Nn + n];
    part[(size_t)b*Nn + n] = run;
    run += v;
  }
}
__global__ void kscan(const int* __restrict__ cnt, int Nn, int* __restrict__ rp){
  __shared__ int buf[256];
  __shared__ int carry;
  int t = threadIdx.x;
  if (t == 0) carry = 0;
  __syncthreads();
  for (int base = 0; base < Nn; base += 256){
    int v = (base + t < Nn) ? cnt[base + t] : 0;
    buf[t] = v;
    __syncthreads();
    for (int off = 1; off < 256; off <<= 1){
      int x = (t >= off) ? buf[t - off] : 0;
      __syncthreads();
      buf[t] += x;
      __syncthreads();
    }
    if (base + t < Nn) rp[base + t] = carry + buf[t] - v;
    __syncthreads();
    if (t == 255) carry += buf[255];
    __syncthreads();
  }
  if (t == 0) rp[Nn] = carry;
}
__global__ void kscatter(const int* __restrict__ dst, int E, int Nn,
                         const int* __restrict__ part, const int* __restrict__ rp,
                         int* __restrict__ eidx){
  int b = blockIdx.x;
  int per = (E + NB_SORT - 1) / NB_SORT;
  int s = b*per, e_end = s + per; if (e_end > E) e_end = E;
  __shared__ int cur[SORT_BINS];
  for (int base = 0; base < Nn; base += SORT_BINS){
    for (int i = threadIdx.x; i < SORT_BINS; i += 256) cur[i] = 0;
    __syncthreads();
    for (int e = s + threadIdx.x; e < e_end; e += 256){
      int d = dst[e] - base;
      if (d >= 0 && d < SORT_BINS){
        int lr = atomicAdd(&cur[d], 1);
        eidx[rp[base + d] + part[(size_t)b*Nn + base + d] + lr] = e;
      }
    }
    __syncthreads();
  }
}

// ======== FAST PATH (all f32) ========

// node GEMMs (f32): uu = x@W1d + b1 ; vv = x@W1bot
template<int CP, int C>
__launch_bounds__(256)
__global__ void knode_f32(const float* __restrict__ W1d, const float* __restrict__ W1b,
                          const float* __restrict__ b1, const float* __restrict__ x,
                          float* __restrict__ uu, float* __restrict__ vv, int Nn){
  constexpr int NP = C / 64;
  __shared__ float A[16][CP + 1];
  int t = threadIdx.x, el = t & 15, grp = t >> 4;
  int r0 = blockIdx.x * 16;
  for (int idx = t; idx < 16*CP; idx += 256){
    int r = idx / CP, k = idx - r*CP;
    int rr = r0 + r;
    A[r][k] = (rr < Nn) ? x[(size_t)rr*CP + k] : 0.f;
  }
  __syncthreads();
  float au[NP][4], av[NP][4];
  #pragma unroll
  for (int p = 0; p < NP; ++p)
    #pragma unroll
    for (int i = 0; i < 4; ++i){
      au[p][i] = b1[p*64 + grp*4 + i];
      av[p][i] = 0.f;
    }
  #pragma unroll 2
  for (int k = 0; k < CP; ++k){
    float a = A[el][k];
    #pragma unroll
    for (int p = 0; p < NP; ++p){
      float4 wd = *reinterpret_cast<const float4*>(&W1d[(size_t)k*C + p*64 + grp*4]);
      float4 wb = *reinterpret_cast<const float4*>(&W1b[(size_t)k*C + p*64 + grp*4]);
      au[p][0] = fmaf(a, wd.x, au[p][0]); au[p][1] = fmaf(a, wd.y, au[p][1]);
      au[p][2] = fmaf(a, wd.z, au[p][2]); au[p][3] = fmaf(a, wd.w, au[p][3]);
      av[p][0] = fmaf(a, wb.x, av[p][0]); av[p][1] = fmaf(a, wb.y, av[p][1]);
      av[p][2] = fmaf(a, wb.z, av[p][2]); av[p][3] = fmaf(a, wb.w, av[p][3]);
    }
  }
  int rr = r0 + el;
  if (rr < Nn){
    #pragma unroll
    for (int p = 0; p < NP; ++p){
      int c = p*64 + grp*4;
      float4 ou; ou.x = au[p][0]; ou.y = au[p][1]; ou.z = au[p][2]; ou.w = au[p][3];
      float4 ov; ov.x = av[p][0]; ov.y = av[p][1]; ov.z = av[p][2]; ov.w = av[p][3];
      *reinterpret_cast<float4*>(&uu[(size_t)rr*C + c]) = ou;
      *reinterpret_cast<float4*>(&vv[(size_t)rr*C + c]) = ov;
    }
  }
}

// BN1 stats: sum/sumsq of relu(uu_i + vv_j) over all edges, per channel.
template<int C>
__launch_bounds__(256)
__global__ void kh1stats(const float* __restrict__ uu, const float* __restrict__ vv,
                         const int* __restrict__ src, const int* __restrict__ dst,
                         const int* __restrict__ eidx, int E, float* __restrict__ statp)
{
  constexpr int CLOG  = (C==64)?6:(C==128)?7:8;
  constexpr int RSTEP = 256 >> CLOG;
  const int t = threadIdx.x;
  const int kcol = t & (C-1), rb = t >> CLOG;
  int per = (E + gridDim.x - 1) / gridDim.x;
  int s0 = blockIdx.x * per;
  int s1 = s0 + per; if (s1 > E) s1 = E;
  float sa = 0.f, qa = 0.f;
  for (int es = s0 + rb; es < s1; es += RSTEP){
    int e = eidx[es];
    int i = dst[e], j = src[e];
    float a = fmaxf(uu[(size_t)i*C + kcol] + vv[(size_t)j*C + kcol], 0.f);
    sa += a; qa += a*a;
  }
  __shared__ float red[256];
  red[t] = sa;
  __syncthreads();
  if (t < C){
    float x = 0.f;
    #pragma unroll
    for (int r = 0; r < RSTEP; ++r) x += red[t + r*C];
    statp[(size_t)blockIdx.x*2*C + t] = x;
  }
  __syncthreads();
  red[t] = qa;
  __syncthreads();
  if (t < C){
    float x = 0.f;
    #pragma unroll
    for (int r = 0; r < RSTEP; ++r) x += red[t + r*C];
    statp[(size_t)blockIdx.x*2*C + C + t] = x;
  }
}

// fused layer-2 (f32, TE=32, EPL=2): gather H1, GEMM, stats, per-node max
// via LDS int atomicMax. nm stride C+1 (bank-conflict fix). unroll 2.
template<int C>
__launch_bounds__(256)
__global__ void kfused_g2(const float* __restrict__ W2, const float* __restrict__ b2,
                          const float* __restrict__ sc1, const float* __restrict__ sh1,
                          const float* __restrict__ uu, const float* __restrict__ vv,
                          const int* __restrict__ src, const int* __restrict__ dst,
                          const int* __restrict__ eidx, const int* __restrict__ rp,
                          int Nn, float* __restrict__ nodemax, float* __restrict__ statp)
{
  constexpr int NT  = 16;
  constexpr int TE  = 32;
  constexpr int EPL = 2;
  constexpr int NP  = C / 64;
  constexpr int CS  = C + 1;           // padded stride for nm
  __shared__ float H1[TE][C + 1];
  __shared__ int   nm[NT*CS];
  __shared__ float red[16][64];
  __shared__ int Si[TE], Sj[TE], LNs[TE];

  int t = threadIdx.x, el = t & 15, grp = t >> 4;
  int n0 = blockIdx.x * NT;
  int e_begin = rp[n0];
  int e_end   = rp[n0 + NT];

  for (int i = t; i < NT*CS; i += 256) nm[i] = 0;

  float sv[NP][4], qv[NP][4];
  #pragma unroll
  for (int p = 0; p < NP; ++p)
    #pragma unroll
    for (int i = 0; i < 4; ++i){ sv[p][i] = 0.f; qv[p][i] = 0.f; }

  for (int tile = e_begin; tile < e_end; tile += TE){
    int nrows = e_end - tile; if (nrows > TE) nrows = TE;
    __syncthreads();                 // prev tile's H1 readers + nm init done
    if (t < TE){
      if (t < nrows){
        int e = eidx[tile + t];
        int d_ = dst[e];
        Si[t] = d_; Sj[t] = src[e];
        int lnv = d_ - n0;
        LNs[t] = (lnv < 0) ? 0 : (lnv > NT-1 ? NT-1 : lnv);
      } else { Si[t] = 0; Sj[t] = 0; LNs[t] = 0; }
    }
    __syncthreads();
    // H1 gather
    for (int idx = t; idx < TE*C; idx += 256){
      int r = idx / C, c = idx - r*C;
      float v = 0.f;
      if (r < nrows){
        int ii = Si[r], jj = Sj[r];
        v = fmaxf(uu[(size_t)ii*C + c] + vv[(size_t)jj*C + c], 0.f) * sc1[c] + sh1[c];
      }
      H1[r][c] = v;
    }
    __syncthreads();
    // layer-2 GEMM (EPL=2) + stats + per-node atomicMax
    float acc[NP][EPL][4];
    #pragma unroll
    for (int p = 0; p < NP; ++p)
      #pragma unroll
      for (int i = 0; i < 4; ++i){
        float b = b2[p*64 + grp*4 + i];
        #pragma unroll
        for (int q = 0; q < EPL; ++q) acc[p][q][i] = b;
      }
    #pragma unroll 2
    for (int k = 0; k < C; ++k){
      float a[EPL];
      #pragma unroll
      for (int q = 0; q < EPL; ++q) a[q] = H1[el + q*16][k];
      #pragma unroll
      for (int p = 0; p < NP; ++p){
        float4 w = *reinterpret_cast<const float4*>(&W2[(size_t)k*C + p*64 + grp*4]);
        #pragma unroll
        for (int q = 0; q < EPL; ++q){
          acc[p][q][0] = fmaf(a[q], w.x, acc[p][q][0]);
          acc[p][q][1] = fmaf(a[q], w.y, acc[p][q][1]);
          acc[p][q][2] = fmaf(a[q], w.z, acc[p][q][2]);
          acc[p][q][3] = fmaf(a[q], w.w, acc[p][q][3]);
        }
      }
    }
    #pragma unroll
    for (int q = 0; q < EPL; ++q){
      int row = el + q*16;
      if (row < nrows){
        int base = LNs[row]*CS;
        #pragma unroll
        for (int p = 0; p < NP; ++p){
          int c = p*64 + grp*4;
          #pragma unroll
          for (int i = 0; i < 4; ++i){
            float v = fmaxf(acc[p][q][i], 0.f);
            sv[p][i] += v; qv[p][i] += v*v;
            atomicMax(&nm[base + c + i], __float_as_int(v));
          }
        }
      }
    }
  }
  __syncthreads();
  for (int idx = t; idx < NT*C; idx += 256){
    int ln = idx / C, c = idx - ln*C;
    nodemax[(size_t)(n0+ln)*C + c] = __int_as_float(nm[ln*CS + c]);
  }
  for (int p = 0; p < NP; ++p){
    __syncthreads();
    #pragma unroll
    for (int i = 0; i < 4; ++i) red[el][grp*4 + i] = sv[p][i];
    __syncthreads();
    if (t < 64){
      float a = 0.f;
      for (int e2 = 0; e2 < 16; ++e2) a += red[e2][t];
      statp[(size_t)blockIdx.x*2*C + p*64 + t] = a;
    }
    __syncthreads();
    #pragma unroll
    for (int i = 0; i < 4; ++i) red[el][grp*4 + i] = qv[p][i];
    __syncthreads();
    if (t < 64){
      float a = 0.f;
      for (int e2 = 0; e2 < 16; ++e2) a += red[e2][t];
      statp[(size_t)blockIdx.x*2*C + C + p*64 + t] = a;
    }
  }
}

// ======== PROVEN f32 kernels (fallback path) ========

template<int CIN, int C, int MODE>
__launch_bounds__(256)
__global__ void kstats1(const float* __restrict__ W1, const float* __restrict__ b1,
                        const float* __restrict__ in0, const float* __restrict__ posf,
                        const float* __restrict__ featf, const int* __restrict__ src,
                        const int* __restrict__ dst, int E, float* __restrict__ statp){
  constexpr int NP = C / 64;
  constexpr int CP = CIN / 2;
  __shared__ float A1[32][CIN + 1];
  __shared__ int Si[32], Sj[32];
  __shared__ float red[16][64];
  int t = threadIdx.x, el = t & 15, grp = t >> 4;
  float sv[NP][4], qv[NP][4];
  #pragma unroll
  for (int p = 0; p < NP; ++p)
    #pragma unroll
    for (int i = 0; i < 4; ++i){ sv[p][i] = 0.f; qv[p][i] = 0.f; }

  int ntiles = (E + 31) / 32;
  for (int tt = blockIdx.x; tt < ntiles; tt += gridDim.x){
    int tile = tt * 32;
    int nrows = E - tile; if (nrows > 32) nrows = 32;
    __syncthreads();
    if (t < 32){
      if (t < nrows){ Si[t] = dst[tile + t]; Sj[t] = src[tile + t]; }
      else { Si[t] = 0; Sj[t] = 0; }
    }
    __syncthreads();
    for (int idx = t; idx < 32*CIN; idx += 256){
      int r = idx / CIN, k = idx - r*CIN;
      float v = 0.f;
      if (r < nrows){
        int i = Si[r], j = Sj[r];
        v = (k < CP) ? in0[(size_t)i*CP + k]
                     : in0[(size_t)j*CP + (k-CP)] - in0[(size_t)i*CP + (k-CP)];
      }
      A1[r][k] = v;
    }
    __syncthreads();
    float acc[NP][2][4];
    #pragma unroll
    for (int p = 0; p < NP; ++p)
      #pragma unroll
      for (int i = 0; i < 4; ++i){ float b = b1[p*64 + grp*4 + i]; acc[p][0][i] = b; acc[p][1][i] = b; }
    #pragma unroll 2
    for (int k = 0; k < CIN; ++k){
      float a0 = A1[el][k], a1 = A1[el+16][k];
      #pragma unroll
      for (int p = 0; p < NP; ++p){
        float4 w = *reinterpret_cast<const float4*>(&W1[(size_t)k*C + p*64 + grp*4]);
        acc[p][0][0] = fmaf(a0, w.x, acc[p][0][0]); acc[p][0][1] = fmaf(a0, w.y, acc[p][0][1]);
        acc[p][0][2] = fmaf(a0, w.z, acc[p][0][2]); acc[p][0][3] = fmaf(a0, w.w, acc[p][0][3]);
        acc[p][1][0] = fmaf(a1, w.x, acc[p][1][0]); acc[p][1][1] = fmaf(a1, w.y, acc[p][1][1]);
        acc[p][1][2] = fmaf(a1, w.z, acc[p][1][2]); acc[p][1][3] = fmaf(a1, w.w, acc[p][1][3]);
      }
    }
    #pragma unroll
    for (int p = 0; p < NP; ++p)
      #pragma unroll
      for (int q = 0; q < 2; ++q){
        int row = el + q*16;
        if (row < nrows){
          #pragma unroll
          for (int i = 0; i < 4; ++i){
            float v = fmaxf(acc[p][q][i], 0.f);
            sv[p][i] += v; qv[p][i] += v*v;
          }
        }
      }
  }
  for (int p = 0; p < NP; ++p){
    __syncthreads();
    #pragma unroll
    for (int i = 0; i < 4; ++i) red[el][grp*4 + i] = sv[p][i];
    __syncthreads();
    if (t < 64){
      float a = 0.f;
      for (int e2 = 0; e2 < 16; ++e2) a += red[e2][t];
      statp[(size_t)blockIdx.x*2*C + p*64 + t] = a;
    }
    __syncthreads();
    #pragma unroll
    for (int i = 0; i < 4; ++i) red[el][grp*4 + i] = qv[p][i];
    __syncthreads();
    if (t < 64){
      float a = 0.f;
      for (int e2 = 0; e2 < 16; ++e2) a += red[e2][t];
      statp[(size_t)blockIdx.x*2*C + C + p*64 + t] = a;
    }
  }
}

template<int CIN, int C, int TE>
__launch_bounds__(256)
__global__ void kfused(const float* __restrict__ W1, const float* __restrict__ b1,
                       const float* __restrict__ W2, const float* __restrict__ b2,
                       const float* __restrict__ sc1, const float* __restrict__ sh1,
                       const float* __restrict__ in0,
                       const int* __restrict__ src, const int* __restrict__ dst,
                       const int* __restrict__ eidx, const int* __restrict__ rp,
                       float* __restrict__ nodemax, float* __restrict__ statp)
{
  constexpr int NT  = 16;
  constexpr int EPL = TE / 16;
  constexpr int NP  = C / 64;
  constexpr int CP  = CIN / 2;
  __shared__ float A1[TE][CIN + 1];
  __shared__ float H1[TE][C + 1];
  __shared__ float NM[NT][C];
  __shared__ float red[16][64];
  __shared__ int Si[TE], Sj[TE];
  float* H2 = &A1[0][0];

  int t = threadIdx.x, el = t & 15, grp = t >> 4;
  int n0 = blockIdx.x * NT;
  int e_begin = rp[n0];
  int e_end   = rp[n0 + NT];

  for (int i = t; i < NT*C; i += 256) (&NM[0][0])[i] = -INFINITY;

  float s2[NP][4], q2[NP][4];
  #pragma unroll
  for (int p = 0; p < NP; ++p)
    #pragma unroll
    for (int i = 0; i < 4; ++i){ s2[p][i] = 0.f; q2[p][i] = 0.f; }

  for (int tile = e_begin; tile < e_end; tile += TE){
    int nrows = e_end - tile; if (nrows > TE) nrows = TE;
    __syncthreads();
    if (t < TE){
      if (t < nrows){ int e = eidx[tile + t]; Si[t] = dst[e]; Sj[t] = src[e]; }
      else { Si[t] = 0; Sj[t] = 0; }
    }
    __syncthreads();
    for (int idx = t; idx < TE*CIN; idx += 256){
      int r = idx / CIN, k = idx - r*CIN;
      float v = 0.f;
      if (r < nrows){
        int i = Si[r], j = Sj[r];
        v = (k < CP) ? in0[(size_t)i*CP + k]
                     : in0[(size_t)j*CP + (k-CP)] - in0[(size_t)i*CP + (k-CP)];
      }
      A1[r][k] = v;
    }
    __syncthreads();
    {
      float acc[NP][EPL][4];
      #pragma unroll
      for (int p = 0; p < NP; ++p)
        #pragma unroll
        for (int i = 0; i < 4; ++i){
          float b = b1[p*64 + grp*4 + i];
          #pragma unroll
          for (int q = 0; q < EPL; ++q) acc[p][q][i] = b;
        }
      #pragma unroll 2
      for (int k = 0; k < CIN; ++k){
        float a[EPL];
        #pragma unroll
        for (int q = 0; q < EPL; ++q) a[q] = A1[el + q*16][k];
        #pragma unroll
        for (int p = 0; p < NP; ++p){
          float4 w = *reinterpret_cast<const float4*>(&W1[(size_t)k*C + p*64 + grp*4]);
          #pragma unroll
          for (int q = 0; q < EPL; ++q){
            acc[p][q][0] = fmaf(a[q], w.x, acc[p][q][0]);
            acc[p][q][1] = fmaf(a[q], w.y, acc[p][q][1]);
            acc[p][q][2] = fmaf(a[q], w.z, acc[p][q][2]);
            acc[p][q][3] = fmaf(a[q], w.w, acc[p][q][3]);
          }
        }
      }
      #pragma unroll
      for (int p = 0; p < NP; ++p)
        #pragma unroll
        for (int q = 0; q < EPL; ++q){
          int row = el + q*16;
          if (row < nrows){
            int c = p*64 + grp*4;
            #pragma unroll
            for (int i = 0; i < 4; ++i)
              H1[row][c+i] = fmaxf(acc[p][q][i], 0.f) * sc1[c+i] + sh1[c+i];
          }
        }
    }
    __syncthreads();
    {
      float acc[NP][EPL][4];
      #pragma unroll
      for (int p = 0; p < NP; ++p)
        #pragma unroll
        for (int i = 0; i < 4; ++i){
          float b = b2[p*64 + grp*4 + i];
          #pragma unroll
          for (int q = 0; q < EPL; ++q) acc[p][q][i] = b;
        }
      #pragma unroll 2
      for (int k = 0; k < C; ++k){
        float a[EPL];
        #pragma unroll
        for (int q = 0; q < EPL; ++q) a[q] = H1[el + q*16][k];
        #pragma unroll
        for (int p = 0; p < NP; ++p){
          float4 w = *reinterpret_cast<const float4*>(&W2[(size_t)k*C + p*64 + grp*4]);
          #pragma unroll
          for (int q = 0; q < EPL; ++q){
            acc[p][q][0] = fmaf(a[q], w.x, acc[p][q][0]);
            acc[p][q][1] = fmaf(a[q], w.y, acc[p][q][1]);
            acc[p][q][2] = fmaf(a[q], w.z, acc[p][q][2]);
            acc[p][q][3] = fmaf(a[q], w.w, acc[p][q][3]);
          }
        }
      }
      #pragma unroll
      for (int p = 0; p < NP; ++p)
        #pragma unroll
        for (int q = 0; q < EPL; ++q){
          int row = el + q*16;
          if (row < nrows){
            int c = p*64 + grp*4;
            #pragma unroll
            for (int i = 0; i < 4; ++i){
              float v = fmaxf(acc[p][q][i], 0.f);
              s2[p][i] += v; q2[p][i] += v*v;
              H2[row*(C+1) + c + i] = v;
            }
          }
        }
    }
    __syncthreads();
    for (int idx = t; idx < NT*C; idx += 256){
      int ln = idx / C, c = idx - ln*C;
      int n = n0 + ln;
      int lo = rp[n];   if (lo < tile) lo = tile;
      int hi = rp[n+1]; if (hi > tile + nrows) hi = tile + nrows;
      lo -= tile; hi -= tile;
      if (lo < hi){
        float m = NM[ln][c];
        for (int r = lo; r < hi; ++r) m = fmaxf(m, H2[r*(C+1) + c]);
        NM[ln][c] = m;
      }
    }
  }
  __syncthreads();
  for (int idx = t; idx < NT*C; idx += 256){
    int ln = idx / C, c = idx - ln*C;
    nodemax[(size_t)(n0+ln)*C + c] = NM[ln][c];
  }
  for (int p = 0; p < NP; ++p){
    __syncthreads();
    #pragma unroll
    for (int i = 0; i < 4; ++i) red[el][grp*4 + i] = s2[p][i];
    __syncthreads();
    if (t < 64){
      float a = 0.f;
      for (int e2 = 0; e2 < 16; ++e2) a += red[e2][t];
      statp[(size_t)blockIdx.x*2*C + p*64 + t] = a;
    }
    __syncthreads();
    #pragma unroll
    for (int i = 0; i < 4; ++i) red[el][grp*4 + i] = q2[p][i];
    __syncthreads();
    if (t < 64){
      float a = 0.f;
      for (int e2 = 0; e2 < 16; ++e2) a += red[e2][t];
      statp[(size_t)blockIdx.x*2*C + C + p*64 + t] = a;
    }
  }
}

// ---------------- stats reduce + BN finalize ----------------
__global__ void kstatred(const float* __restrict__ statp, int nblk, int C,
                         float* __restrict__ gs, float* __restrict__ gq){
  int c = blockIdx.x;
  float s = 0.f, q = 0.f;
  for (int b = threadIdx.x; b < nblk; b += 256){
    s += statp[(size_t)b*2*C + c];
    q += statp[(size_t)b*2*C + C + c];
  }
  __shared__ float ls[256], lq[256];
  ls[threadIdx.x] = s; lq[threadIdx.x] = q;
  __syncthreads();
  for (int o = 128; o; o >>= 1){
    if (threadIdx.x < o){ ls[threadIdx.x] += ls[threadIdx.x+o]; lq[threadIdx.x] += lq[threadIdx.x+o]; }
    __syncthreads();
  }
  if (threadIdx.x == 0){ gs[c] = ls[0]; gq[c] = lq[0]; }
}
__global__ void finalize_bn(const float* __restrict__ gs, const float* __restrict__ gq,
                            const float* __restrict__ g, const float* __restrict__ be,
                            float invR, float* __restrict__ sc, float* __restrict__ sh){
  int c = threadIdx.x;
  float m  = gs[c] * invR;
  float va = gq[c] * invR - m*m;
  float s  = g[c] * rsqrtf(va + 1e-5f);
  sc[c] = s;
  sh[c] = be[c] - m*s;
}

// ---------------- BN affine on node maxima ----------------
template<int C>
__global__ void kaffine(const float* __restrict__ nodemax, const int* __restrict__ rp,
                        const float* __restrict__ sc, const float* __restrict__ sh,
                        float* __restrict__ xo, int Nn){
  int i = blockIdx.x*256 + threadIdx.x;
  if (i >= Nn*C) return;
  int n = i / C, c = i - n*C;
  float v = 0.f;
  if (rp[n+1] > rp[n]) v = nodemax[i] * sc[c] + sh[c];
  xo[i] = v;
}

// ---------------- per-graph segment max of x123 (two-phase parallel) ----------------
__global__ void kxg_part(const float* __restrict__ x1, const float* __restrict__ x2,
                         const float* __restrict__ x3, const int* __restrict__ gptr,
                         float* __restrict__ xgpart){
  int g = blockIdx.x, ch = blockIdx.y;
  int t = threadIdx.x;
  int s = gptr[g], e = gptr[g+1];
  int len = e - s, per = (len + 31) / 32;
  int n0 = s + ch*per, n1 = n0 + per; if (n1 > e) n1 = e;
  float mx0 = -INFINITY, mx1 = -INFINITY;
  int c0 = t, c1 = t + 256;
  for (int n = n0; n < n1; ++n){
    float v0 = (c0 < 64)  ? x1[(size_t)n*64  + c0]
             : (c0 < 192) ? x2[(size_t)n*128 + (c0 - 64)]
                          : x3[(size_t)n*256 + (c0 - 192)];
    mx0 = fmaxf(mx0, v0);
    if (c1 < 448){
      float v1 = x3[(size_t)n*256 + (c1 - 192)];
      mx1 = fmaxf(mx1, v1);
    }
  }
  xgpart[(size_t)(g*32 + ch)*448 + c0] = mx0;
  if (c1 < 448) xgpart[(size_t)(g*32 + ch)*448 + c1] = mx1;
}
__global__ void kxg_red(const float* __restrict__ xgpart, const int* __restrict__ gptr,
                        float* __restrict__ xg){
  int g = blockIdx.x;
  int c = blockIdx.y * 256 + threadIdx.x;
  if (c >= 448) return;
  float mx = -INFINITY;
  for (int ch = 0; ch < 32; ++ch)
    mx = fmaxf(mx, xgpart[(size_t)(g*32 + ch)*448 + c]);
  xg[g*448 + c] = (gptr[g+1] > gptr[g] && !__builtin_isinf(mx)) ? mx : 0.f;
}

// ---------------- m1 ----------------
__launch_bounds__(256)
__global__ void km1(const float* __restrict__ Wf, const float* __restrict__ bias,
                    const float* __restrict__ x1, const float* __restrict__ x2,
                    const float* __restrict__ x3, float* __restrict__ x4p,
                    float* __restrict__ statp, int Nn){
  __shared__ float A[16][449];
  __shared__ float red[16][64];
  int t = threadIdx.x, el = t & 15, grp = t >> 4;
  int r0 = blockIdx.x * 16;
  for (int idx = t; idx < 16*448; idx += 256){
    int r = idx / 448, k = idx - r*448;
    int rr = r0 + r;
    float v = 0.f;
    if (rr < Nn)
      v = (k < 64)  ? x1[(size_t)rr*64  + k]
        : (k < 192) ? x2[(size_t)rr*128 + (k - 64)]
                    : x3[(size_t)rr*256 + (k - 192)];
    A[r][k] = v;
  }
  __syncthreads();
  float sv[4][4], qv[4][4];
  float acc[4][4];
  #pragma unroll
  for (int p = 0; p < 4; ++p)
    #pragma unroll
    for (int i = 0; i < 4; ++i){
      sv[p][i] = 0.f; qv[p][i] = 0.f;
      acc[p][i] = bias[p*64 + grp*4 + i];
    }
  #pragma unroll 2
  for (int k = 0; k < 448; ++k){
    float a = A[el][k];
    #pragma unroll
    for (int p = 0; p < 4; ++p){
      float4 w = *reinterpret_cast<const float4*>(&Wf[(size_t)k*256 + p*64 + grp*4]);
      acc[p][0] = fmaf(a, w.x, acc[p][0]); acc[p][1] = fmaf(a, w.y, acc[p][1]);
      acc[p][2] = fmaf(a, w.z, acc[p][2]); acc[p][3] = fmaf(a, w.w, acc[p][3]);
    }
  }
  int rr = r0 + el;
  #pragma unroll
  for (int p = 0; p < 4; ++p){
    if (rr < Nn){
      int c = p*64 + grp*4;
      float v0 = fmaxf(acc[p][0],0.f), v1 = fmaxf(acc[p][1],0.f);
      float v2 = fmaxf(acc[p][2],0.f), v3 = fmaxf(acc[p][3],0.f);
      sv[p][0]=v0; sv[p][1]=v1; sv[p][2]=v2; sv[p][3]=v3;
      qv[p][0]=v0*v0; qv[p][1]=v1*v1; qv[p][2]=v2*v2; qv[p][3]=v3*v3;
      float4 o; o.x=v0; o.y=v1; o.z=v2; o.w=v3;
      *reinterpret_cast<float4*>(&x4p[(size_t)rr*256 + c]) = o;
    }
  }
  for (int p = 0; p < 4; ++p){
    __syncthreads();
    #pragma unroll
    for (int i = 0; i < 4; ++i) red[el][grp*4 + i] = sv[p][i];
    __syncthreads();
    if (t < 64){
      float a = 0.f;
      for (int e2 = 0; e2 < 16; ++e2) a += red[e2][t];
      statp[(size_t)blockIdx.x*512 + p*64 + t] = a;
    }
    __syncthreads();
    #pragma unroll
    for (int i = 0; i < 4; ++i) red[el][grp*4 + i] = qv[p][i];
    __syncthreads();
    if (t < 64){
      float a = 0.f;
      for (int e2 = 0; e2 < 16; ++e2) a += red[e2][t];
      statp[(size_t)blockIdx.x*512 + 256 + p*64 + t] = a;
    }
  }
}

// ---------------- m2 + bn8 ----------------
__global__ void m2_mlp(const float* __restrict__ xg, const float* __restrict__ Wf,
                       const float* __restrict__ b, float* __restrict__ u_pre){
  __shared__ float row[448];
  int g = blockIdx.x, t = threadIdx.x;
  for (int k = t; k < 448; k += 256) row[k] = xg[g*448 + k];
  __syncthreads();
  float acc = b[t];
  #pragma unroll 4
  for (int k = 0; k < 448; ++k) acc = fmaf(row[k], Wf[(size_t)k*256 + t], acc);
  u_pre[g*256 + t] = fmaxf(acc, 0.f);
}
__global__ void bn8(const float* __restrict__ u_pre, const float* __restrict__ g,
                    const float* __restrict__ be, float* __restrict__ u_bn){
  int c = threadIdx.x;
  float s = 0.f, q = 0.f;
  for (int r = 0; r < 8; ++r){ float v = u_pre[r*256 + c]; s += v; q += v*v; }
  float m  = s * 0.125f;
  float va = q * 0.125f - m*m;
  float scl = g[c] * rsqrtf(va + 1e-5f);
  float sht = be[c] - m*scl;
  for (int r = 0; r < 8; ++r) u_bn[r*256 + c] = u_pre[r*256 + c]*scl + sht;
}

// ---------------- einsum ----------------
__global__ void keinsum(const float* __restrict__ x4p, const float* __restrict__ sc4,
                        const float* __restrict__ sh4, const float* __restrict__ hmf,
                        const int* __restrict__ gptr, float* __restrict__ x6part){
  int g = blockIdx.x, s32 = blockIdx.y, c = threadIdx.x;
  int s = gptr[g], e = gptr[g+1];
  int len = e - s;
  int per = (len + 31) / 32;
  int n0 = s + s32*per;
  int n1 = n0 + per; if (n1 > e) n1 = e;
  float scl = sc4[c], shf = sh4[c];
  float acc[24];
  #pragma unroll
  for (int i = 0; i < 24; ++i) acc[i] = 0.f;
  __shared__ float hrow[16][24];
  for (int nb = n0; nb < n1; nb += 16){
    int cntn = n1 - nb; if (cntn > 16) cntn = 16;
    __syncthreads();
    for (int i = threadIdx.x; i < cntn*24; i += 256)
      hrow[i/24][i%24] = hmf[(size_t)nb*24 + i];
    __syncthreads();
    for (int j = 0; j < cntn; ++j){
      float a = x4p[(size_t)(nb+j)*256 + c] * scl + shf;
      #pragma unroll
      for (int i = 0; i < 24; ++i) acc[i] = fmaf(a, hrow[j][i], acc[i]);
    }
  }
  #pragma unroll
  for (int i = 0; i < 24; ++i)
    x6part[((size_t)(g*32 + s32)*24 + i)*256 + c] = acc[i];
}
__global__ void keired(const float* __restrict__ x6part, float* __restrict__ x6p){
  int gk = blockIdx.x;
  int g = gk / 24, k = gk - g*24, c = threadIdx.x;
  float a = 0.f;
  for (int s32 = 0; s32 < 32; ++s32)
    a += x6part[((size_t)(g*32 + s32)*24 + k)*256 + c];
  x6p[(size_t)gk*256 + c] = a;
}

// ---------------- final linear + relu + BN (f32 output) ----------------
__global__ void lin_relu_k(const float* __restrict__ x6p, const float* __restrict__ u_bn,
                           const float* __restrict__ hs, const float* __restrict__ Wf,
                           const float* __restrict__ b, float* __restrict__ x7p){
  __shared__ float row[512];
  int r = blockIdx.x, t = threadIdx.x;
  int g = r / 24, kk = r - g*24;
  row[t]       = x6p[(size_t)r*256 + t];
  row[256 + t] = u_bn[g*256 + t] * hs[g*24 + kk];
  __syncthreads();
  float acc = b[t];
  #pragma unroll 4
  for (int k = 0; k < 512; ++k) acc = fmaf(row[k], Wf[(size_t)k*256 + t], acc);
  x7p[(size_t)r*256 + t] = fmaxf(acc, 0.f);
}
__global__ void final_bn_k(const float* __restrict__ x7p, const float* __restrict__ g,
                           const float* __restrict__ be, float* __restrict__ out){
  int c = threadIdx.x;
  float s = 0.f, q = 0.f;
  for (int r = 0; r < 192; ++r){ float v = x7p[(size_t)r*256 + c]; s += v; q += v*v; }
  const float inv = 1.f / 192.f;
  float m  = s * inv;
  float va = q * inv - m*m;
  float scl = g[c] * rsqrtf(va + 1e-5f);
  float sht = be[c] - m*scl;
  for (int r = 0; r < 192; ++r)
    out[(size_t)r*256 + c] = x7p[(size_t)r*256 + c]*scl + sht;
}

__global__ void kerr(float* out, float code){ if (threadIdx.x == 0) out[0] = code; }

extern "C" void kernel_launch(void* const* d_in, const int* in_sizes, int n_in,
                              void* d_out, int out_size, void* d_ws, size_t ws_size,
                              hipStream_t stream)
{
  const int N = in_sizes[0] / 3;
  const int E = in_sizes[3] / 2;
  float* outf = (float*)d_out;

  // ---- host-side input-map verification ----
  {
    const int co_[3] = {64,128,256};
    int exp41[41];
    exp41[0]=N*3; exp41[1]=N*61; exp41[2]=N*24; exp41[3]=2*E; exp41[4]=N;
    int idx=5;
    for (int i=0;i<3;++i){
      int ci = (i==0)?128:(i==1)?128:256;
      exp41[idx++]=ci*co_[i]; exp41[idx++]=co_[i]; exp41[idx++]=co_[i]; exp41[idx++]=co_[i];
      exp41[idx++]=co_[i]*co_[i]; exp41[idx++]=co_[i]; exp41[idx++]=co_[i]; exp41[idx++]=co_[i];
    }
    for (int r=0;r<2;++r){ exp41[idx++]=448*256; exp41[idx++]=256; exp41[idx++]=256; exp41[idx++]=256; }
    exp41[idx++]=512*256; exp41[idx++]=256; exp41[idx++]=256; exp41[idx++]=256;
    int bad = -1;
    if (n_in != 41) bad = 99;
    else for (int i=0;i<41;++i) if (in_sizes[i] != exp41[i]){ bad = i; break; }
    if (bad >= 0){
      kerr<<<1, 64, 0, stream>>>(outf, 100000.f + (float)bad);
      return;
    }
  }

  const int*  tei   = (const int*)d_in[3];
  const int*  batch = (const int*)d_in[4];
  const int*  srcp  = tei;
  const int*  dstp  = tei + E;

  char* base = (char*)d_ws;
  size_t off = 0;
  auto alloc = [&](size_t bytes) -> void* {
    void* p = base + off;
    off = (off + bytes + 255) & ~((size_t)255);
    return p;
  };

  int* flag = (int*)alloc(256);

  float* posf  = (float*)alloc((size_t)N*3*4);
  float* featf = (float*)alloc((size_t)N*61*4);
  float* hmf   = (float*)alloc((size_t)N*24*4);
  float* x0f   = (float*)alloc((size_t)N*64*4);
  float* w1f[3]; float* w2f[3];
  float* b1f[3]; float* g1f[3]; float* be1f[3];
  float* b2ff[3]; float* g2f[3]; float* be2f[3];
  float* s1a[3]; float* h1a[3]; float* s2a[3]; float* h2a[3];
  const int cin1[3] = {128, 128, 256};
  const int co[3]   = {64, 128, 256};
  for (int i = 0; i < 3; ++i){
    w1f[i]  = (float*)alloc((size_t)cin1[i]*co[i]*4);
    w2f[i]  = (float*)alloc((size_t)co[i]*co[i]*4);
    b1f[i]  = (float*)alloc(co[i]*4);
    g1f[i]  = (float*)alloc(co[i]*4);
    be1f[i] = (float*)alloc(co[i]*4);
    b2ff[i] = (float*)alloc(co[i]*4);
    g2f[i]  = (float*)alloc(co[i]*4);
    be2f[i] = (float*)alloc(co[i]*4);
    s1a[i]  = (float*)alloc(co[i]*4);
    h1a[i]  = (float*)alloc(co[i]*4);
    s2a[i]  = (float*)alloc(co[i]*4);
    h2a[i]  = (float*)alloc(co[i]*4);
  }
  float* w1df = (float*)alloc((size_t)128*256*4);   // W1top - W1bot (max size)
  float* m1wf = (float*)alloc(448*256*4);
  float* m1bf = (float*)alloc(256*4);
  float* m1gf = (float*)alloc(256*4);
  float* m1bef= (float*)alloc(256*4);
  float* m2wf = (float*)alloc(448*256*4);
  float* m2bf = (float*)alloc(256*4);
  float* m2gf = (float*)alloc(256*4);
  float* m2bef= (float*)alloc(256*4);
  float* linwf= (float*)alloc(512*256*4);
  float* linbf= (float*)alloc(256*4);
  float* bngf = (float*)alloc(256*4);
  float* bnbf = (float*)alloc(256*4);

  float* x1 = (float*)alloc((size_t)N*64*4);
  float* x2 = (float*)alloc((size_t)N*128*4);
  float* nodemax = (float*)alloc((size_t)N*256*4);
  float* x4p = nodemax;                          // alias: nodemax dead before km1

  float* statp = (float*)alloc((size_t)3200*512*4);
  int* part = (int*)alloc((size_t)NB_SORT*N*4);
  int* eidx = (int*)alloc((size_t)E*4);
  int* rp   = (int*)alloc((size_t)(N+1)*4);
  int* cnt  = (int*)alloc((size_t)N*4);
  int* gptr = (int*)alloc(16*4);

  float* gs  = (float*)alloc(256*4);
  float* gq  = (float*)alloc(256*4);
  float* sc4 = (float*)alloc(256*4); float* sh4 = (float*)alloc(256*4);
  float* hs  = (float*)alloc(192*4);

  // ubuf: uu for all GCUs; x3 aliases it (x3 written only after GCU3 done)
  float* ubuf = (float*)alloc((size_t)N*256*4);
  float* x3 = ubuf;

  // vbuf: vv for all GCUs if it fits; post-GCU tail buffers always alias it
  const size_t tailFl = 1793536;                 // floats needed by tail buffers
  const size_t fastB  = (size_t)N*256*4;
  size_t off0 = off;
  int plan = (off0 + fastB + (1u<<20) <= ws_size) ? 1 : 0;
  float* vbuf = (float*)alloc(plan ? fastB : (tailFl*4 + 1024));
  float* x6part = vbuf;
  float* xgpart = vbuf + 1572864;
  float* x6p    = vbuf + 1687552;
  float* x7p    = vbuf + 1736704;
  float* u_pre  = vbuf + 1785856;
  float* u_bn   = vbuf + 1787904;
  float* xg     = vbuf + 1789952;
  (void)out_size;

  kdetect<<<1, 256, 0, stream>>>((const unsigned short*)d_in[0], flag);
  CTab tab;
  int ti = 0;
  auto add = [&](int idx, float* dstp_, int n){ tab.e[ti].s = d_in[idx]; tab.e[ti].d = dstp_; tab.e[ti].n = n; ++ti; };
  add(0, posf,  N*3);
  add(1, featf, N*61);
  add(2, hmf,   N*24);
  for (int i = 0; i < 3; ++i){
    int b0 = 5 + i*8;
    add(b0+0, w1f[i],  cin1[i]*co[i]);
    add(b0+1, b1f[i],  co[i]);
    add(b0+2, g1f[i],  co[i]);
    add(b0+3, be1f[i], co[i]);
    add(b0+4, w2f[i],  co[i]*co[i]);
    add(b0+5, b2ff[i], co[i]);
    add(b0+6, g2f[i],  co[i]);
    add(b0+7, be2f[i], co[i]);
  }
  add(29, m1wf, 448*256); add(30, m1bf, 256); add(31, m1gf, 256); add(32, m1bef, 256);
  add(33, m2wf, 448*256); add(34, m2bf, 256); add(35, m2gf, 256); add(36, m2bef, 256);
  add(37, linwf, 512*256); add(38, linbf, 256); add(39, bngf, 256); add(40, bnbf, 256);
  kconv<<<dim3(64, 39), 256, 0, stream>>>(tab, flag);

  kpack0<<<(N*64 + 255)/256, 256, 0, stream>>>(posf, featf, x0f, N);

  kgptr<<<1, 64, 0, stream>>>(batch, N, gptr);
  khs<<<8, 256, 0, stream>>>(hmf, gptr, hs);

  // ---- parallel counting sort of edges by dst ----
  const int gridN = (N + 255)/256;
  khist<<<NB_SORT, 256, 0, stream>>>(dstp, E, N, part);
  kcnt<<<gridN, 256, 0, stream>>>(part, N, cnt);
  kscan<<<1, 256, 0, stream>>>(cnt, N, rp);
  kpre<<<gridN, 256, 0, stream>>>(part, N);
  kscatter<<<NB_SORT, 256, 0, stream>>>(dstp, E, N, part, rp, eidx);

  const int NBKF = N / 16;
  const int nblk16 = (N + 15) / 16;
  const float invE = 1.f / (float)E;

  if (plan){
    float* uu = ubuf;
    float* vv = vbuf;
    // ---- GCU1: CP=64, C=64 ----
    kwd<<<(64*64 + 255)/256, 256, 0, stream>>>(w1f[0], w1df, 64*64);
    knode_f32<64,64><<<nblk16, 256, 0, stream>>>(w1df, w1f[0] + 64*64, b1f[0], x0f, uu, vv, N);
    kh1stats<64><<<1024, 256, 0, stream>>>(uu, vv, srcp, dstp, eidx, E, statp);
    kstatred<<<64, 256, 0, stream>>>(statp, 1024, 64, gs, gq);
    finalize_bn<<<1, 64, 0, stream>>>(gs, gq, g1f[0], be1f[0], invE, s1a[0], h1a[0]);
    kfused_g2<64><<<NBKF, 256, 0, stream>>>(w2f[0], b2ff[0], s1a[0], h1a[0],
        uu, vv, srcp, dstp, eidx, rp, N, nodemax, statp);
    kstatred<<<64, 256, 0, stream>>>(statp, NBKF, 64, gs, gq);
    finalize_bn<<<1, 64, 0, stream>>>(gs, gq, g2f[0], be2f[0], invE, s2a[0], h2a[0]);
    kaffine<64><<<(N*64 + 255)/256, 256, 0, stream>>>(nodemax, rp, s2a[0], h2a[0], x1, N);
    // ---- GCU2: CP=64, C=128 ----
    kwd<<<(64*128 + 255)/256, 256, 0, stream>>>(w1f[1], w1df, 64*128);
    knode_f32<64,128><<<nblk16, 256, 0, stream>>>(w1df, w1f[1] + 64*128, b1f[1], x1, uu, vv, N);
    kh1stats<128><<<1024, 256, 0, stream>>>(uu, vv, srcp, dstp, eidx, E, statp);
    kstatred<<<128, 256, 0, stream>>>(statp, 1024, 128, gs, gq);
    finalize_bn<<<1, 128, 0, stream>>>(gs, gq, g1f[1], be1f[1], invE, s1a[1], h1a[1]);
    kfused_g2<128><<<NBKF, 256, 0, stream>>>(w2f[1], b2ff[1], s1a[1], h1a[1],
        uu, vv, srcp, dstp, eidx, rp, N, nodemax, statp);
    kstatred<<<128, 256, 0, stream>>>(statp, NBKF, 128, gs, gq);
    finalize_bn<<<1, 128, 0, stream>>>(gs, gq, g2f[1], be2f[1], invE, s2a[1], h2a[1]);
    kaffine<128><<<(N*128 + 255)/256, 256, 0, stream>>>(nodemax, rp, s2a[1], h2a[1], x2, N);
    // ---- GCU3: CP=128, C=256 ----
    kwd<<<(128*256 + 255)/256, 256, 0, stream>>>(w1f[2], w1df, 128*256);
    knode_f32<128,256><<<nblk16, 256, 0, stream>>>(w1df, w1f[2] + 128*256, b1f[2], x2, uu, vv, N);
    kh1stats<256><<<1024, 256, 0, stream>>>(uu, vv, srcp, dstp, eidx, E, statp);
    kstatred<<<256, 256, 0, stream>>>(statp, 1024, 256, gs, gq);
    finalize_bn<<<1, 256, 0, stream>>>(gs, gq, g1f[2], be1f[2], invE, s1a[2], h1a[2]);
    kfused_g2<256><<<NBKF, 256, 0, stream>>>(w2f[2], b2ff[2], s1a[2], h1a[2],
        uu, vv, srcp, dstp, eidx, rp, N, nodemax, statp);
    kstatred<<<256, 256, 0, stream>>>(statp, NBKF, 256, gs, gq);
    finalize_bn<<<1, 256, 0, stream>>>(gs, gq, g2f[2], be2f[2], invE, s2a[2], h2a[2]);
    kaffine<256><<<(N*256 + 255)/256, 256, 0, stream>>>(nodemax, rp, s2a[2], h2a[2], x3, N);
  } else {
    // ---- fallback: known-good R10 f32 path ----
    const int NBK1 = 1024;
    kstats1<128,64,0><<<NBK1, 256, 0, stream>>>(w1f[0], b1f[0], x0f, nullptr, nullptr,
        srcp, dstp, E, statp);
    kstatred<<<64, 256, 0, stream>>>(statp, NBK1, 64, gs, gq);
    finalize_bn<<<1, 64, 0, stream>>>(gs, gq, g1f[0], be1f[0], invE, s1a[0], h1a[0]);
    kfused<128,64,32><<<NBKF, 256, 0, stream>>>(w1f[0], b1f[0], w2f[0], b2ff[0],
        s1a[0], h1a[0], x0f, srcp, dstp, eidx, rp, nodemax, statp);
    kstatred<<<64, 256, 0, stream>>>(statp, NBKF, 64, gs, gq);
    finalize_bn<<<1, 64, 0, stream>>>(gs, gq, g2f[0], be2f[0], invE, s2a[0], h2a[0]);
    kaffine<64><<<(N*64 + 255)/256, 256, 0, stream>>>(nodemax, rp, s2a[0], h2a[0], x1, N);

    kstats1<128,128,0><<<NBK1, 256, 0, stream>>>(w1f[1], b1f[1], x1, nullptr, nullptr,
        srcp, dstp, E, statp);
    kstatred<<<128, 256, 0, stream>>>(statp, NBK1, 128, gs, gq);
    finalize_bn<<<1, 128, 0, stream>>>(gs, gq, g1f[1], be1f[1], invE, s1a[1], h1a[1]);
    kfused<128,128,32><<<NBKF, 256, 0, stream>>>(w1f[1], b1f[1], w2f[1], b2ff[1],
        s1a[1], h1a[1], x1, srcp, dstp, eidx, rp, nodemax, statp);
    kstatred<<<128, 256, 0, stream>>>(statp, NBKF, 128, gs, gq);
    finalize_bn<<<1, 128, 0, stream>>>(gs, gq, g2f[1], be2f[1], invE, s2a[1], h2a[1]);
    kaffine<128><<<(N*128 + 255)/256, 256, 0, stream>>>(nodemax, rp, s2a[1], h2a[1], x2, N);

    kstats1<256,256,0><<<NBK1, 256, 0, stream>>>(w1f[2], b1f[2], x2, nullptr, nullptr,
        srcp, dstp, E, statp);
    kstatred<<<256, 256, 0, stream>>>(statp, NBK1, 256, gs, gq);
    finalize_bn<<<1, 256, 0, stream>>>(gs, gq, g1f[2], be1f[2], invE, s1a[2], h1a[2]);
    kfused<256,256,16><<<NBKF, 256, 0, stream>>>(w1f[2], b1f[2], w2f[2], b2ff[2],
        s1a[2], h1a[2], x2, srcp, dstp, eidx, rp, nodemax, statp);
    kstatred<<<256, 256, 0, stream>>>(statp, NBKF, 256, gs, gq);
    finalize_bn<<<1, 256, 0, stream>>>(gs, gq, g2f[2], be2f[2], invE, s2a[2], h2a[2]);
    kaffine<256><<<(N*256 + 255)/256, 256, 0, stream>>>(nodemax, rp, s2a[2], h2a[2], x3, N);
  }

  // graph pooling (parallel two-phase)
  kxg_part<<<dim3(8, 32), 256, 0, stream>>>(x1, x2, x3, gptr, xgpart);
  kxg_red<<<dim3(8, 2), 256, 0, stream>>>(xgpart, gptr, xg);

  km1<<<NBKF, 256, 0, stream>>>(m1wf, m1bf, x1, x2, x3, x4p, statp, N);
  kstatred<<<256, 256, 0, stream>>>(statp, NBKF, 256, gs, gq);
  finalize_bn<<<1, 256, 0, stream>>>(gs, gq, m1gf, m1bef, 1.f/(float)N, sc4, sh4);

  m2_mlp<<<8, 256, 0, stream>>>(xg, m2wf, m2bf, u_pre);
  bn8<<<1, 256, 0, stream>>>(u_pre, m2gf, m2bef, u_bn);

  keinsum<<<dim3(8, 32), 256, 0, stream>>>(x4p, sc4, sh4, hmf, gptr, x6part);
  keired<<<192, 256, 0, stream>>>(x6part, x6p);

  lin_relu_k<<<192, 256, 0, stream>>>(x6p, u_bn, hs, linwf, linbf, x7p);
  final_bn_k<<<1, 256, 0, stream>>>(x7p, bngf, bnbf, outf);
}

// Round 14
// 5475.610 us; speedup vs baseline: 1.3141x; 1.0327x over previous
//
#include <hip/hip_runtime.h>
#include <hip/hip_bf16.h>
#include <cstdint>

using bf16 = __hip_bfloat16;
#define DI __device__ __forceinline__

DI float b2f(bf16 v){ return __bfloat162float(v); }
DI float us2f(unsigned short u){ bf16 t; *reinterpret_cast<unsigned short*>(&t) = u; return __bfloat162float(t); }

// R24: byte-exact restore of R20 (PASS, 5491us — session best). R23 attributed
// the nm padding as neutral-to-negative (occupancy 30->21%, +3% total), so it
// is reverted. Design: algebraic EdgeConv decomposition (uu/vv node GEMMs),
// gathered-H1 fused layer-2 (TE=32, EPL=2, LDS atomicMax segmented max).
// Output FLOAT32. LDS atomics only.

// ---------------- dtype detection on pos (~N(0,1)) ----------------
__global__ void kdetect(const unsigned short* __restrict__ pos_u, int* __restrict__ flag){
  __shared__ int cE, cO;
  if (threadIdx.x == 0){ cE = 0; cO = 0; }
  __syncthreads();
  int pe = 0, po = 0;
  for (int i = threadIdx.x; i < 2048; i += 256){
    float ve = fabsf(us2f(pos_u[2*i]));
    float vo = fabsf(us2f(pos_u[2*i + 1]));
    if (ve > 1e-4f && ve < 50.f) pe++;
    if (vo > 1e-4f && vo < 50.f) po++;
  }
  atomicAdd(&cE, pe);
  atomicAdd(&cO, po);
  __syncthreads();
  if (threadIdx.x == 0)
    flag[0] = (2*cE < cO) ? 1 : 0;   // 1 => inputs are f32
}

// ---------------- normalize all float inputs to f32 ----------------
struct CEnt { const void* s; float* d; int n; };
struct CTab { CEnt e[39]; };
__global__ void kconv(CTab tab, const int* __restrict__ flag){
  CEnt en = tab.e[blockIdx.y];
  const bool isf32 = (flag[0] != 0);
  for (int i = blockIdx.x*256 + threadIdx.x; i < en.n; i += gridDim.x*256)
    en.d[i] = isf32 ? ((const float*)en.s)[i] : b2f(((const bf16*)en.s)[i]);
}

// ---------------- pack x_in = [pos | feat]  [N][64] ----------------
__global__ void kpack0(const float* __restrict__ posf, const float* __restrict__ featf,
                       float* __restrict__ x0, int Nn){
  int i = blockIdx.x*256 + threadIdx.x;
  if (i >= Nn*64) return;
  int n = i >> 6, c = i & 63;
  x0[i] = (c < 3) ? posf[(size_t)n*3 + c] : featf[(size_t)n*61 + (c-3)];
}

// ---------------- W1d = W1top - W1bot ----------------
__global__ void kwd(const float* __restrict__ W1, float* __restrict__ W1d, int CPC){
  int i = blockIdx.x*256 + threadIdx.x;
  if (i < CPC) W1d[i] = W1[i] - W1[CPC + i];
}

// ---------------- graph partition ----------------
__global__ void kgptr(const int* __restrict__ batch, int Nn, int* __restrict__ gptr){
  int g = threadIdx.x;
  if (g > 8) return;
  if (g == 8){ gptr[8] = Nn; return; }
  int lo = 0, hi = Nn;
  while (lo < hi){ int mid = (lo + hi) >> 1; if (batch[mid] < g) lo = mid + 1; else hi = mid; }
  gptr[g] = lo;
}

// ---------------- per-graph heatmap column sums ----------------
__global__ void khs(const float* __restrict__ hmf, const int* __restrict__ gptr,
                    float* __restrict__ hs){
  int g = blockIdx.x;
  int lane = threadIdx.x % 24, slice = threadIdx.x / 24;
  __shared__ float part[10][24];
  if (threadIdx.x < 240){
    int s = gptr[g], e = gptr[g+1];
    float acc = 0.f;
    for (int n = s + slice; n < e; n += 10) acc += hmf[(size_t)n*24 + lane];
    part[slice][lane] = acc;
  }
  __syncthreads();
  if (threadIdx.x < 24){
    float a = 0.f;
    for (int i = 0; i < 10; ++i) a += part[i][threadIdx.x];
    hs[g*24 + threadIdx.x] = a;
  }
}

// ---------------- parallel counting sort of edges by dst (64 blocks) ----------------
#define NB_SORT 64
#define SORT_BINS 8192
__global__ void khist(const int* __restrict__ dst, int E, int Nn, int* __restrict__ part){
  int b = blockIdx.x;
  int per = (E + NB_SORT - 1) / NB_SORT;
  int s = b*per, e_end = s + per; if (e_end > E) e_end = E;
  __shared__ int h[SORT_BINS];
  for (int base = 0; base < Nn; base += SORT_BINS){
    for (int i = threadIdx.x; i < SORT_BINS; i += 256) h[i] = 0;
    __syncthreads();
    for (int e = s + threadIdx.x; e < e_end; e += 256){
      int d = dst[e] - base;
      if (d >= 0 && d < SORT_BINS) atomicAdd(&h[d], 1);
    }
    __syncthreads();
    int lim = Nn - base; if (lim > SORT_BINS) lim = SORT_BINS;
    for (int i = threadIdx.x; i < lim; i += 256) part[(size_t)b*Nn + base + i] = h[i];
    __syncthreads();
  }
}
__global__ void kcnt(const int* __restrict__ part, int Nn, int* __restrict__ cnt){
  int n = blockIdx.x*256 + threadIdx.x; if (n >= Nn) return;
  int s = 0;
  for (int b = 0; b < NB_SORT; ++b) s += part[(size_t)b*Nn + n];
  cnt[n] = s;
}
__global__ void kpre(int* part, int Nn){
  int n = blockIdx.x*256 + threadIdx.x; if (n >= Nn) return;
  int run = 0;
  for (int b = 0; b < NB_SORT; ++b){
    int v = part[(size_t)b*Nn + n];
    part[(size_t)b*Nn + n] = run;
    run += v;
  }
}
__global__ void kscan(const int* __restrict__ cnt, int Nn, int* __restrict__ rp){
  __shared__ int buf[256];
  __shared__ int carry;
  int t = threadIdx.x;
  if (t == 0) carry = 0;
  __syncthreads();
  for (int base = 0; base < Nn; base += 256){
    int v = (base + t < Nn) ? cnt[base + t] : 0;
    buf[t] = v;
    __syncthreads();
    for (int off = 1; off < 256; off <<= 1){
      int x = (t >= off) ? buf[t - off] : 0;
      __syncthreads();
      buf[t] += x;
      __syncthreads();
    }
    if (base + t < Nn) rp[base + t] = carry + buf[t] - v;
    __syncthreads();
    if (t == 255) carry += buf[255];
    __syncthreads();
  }
  if (t == 0) rp[Nn] = carry;
}
__global__ void kscatter(const int* __restrict__ dst, int E, int Nn,
                         const int* __restrict__ part, const int* __restrict__ rp,
                         int* __restrict__ eidx){
  int b = blockIdx.x;
  int per = (E + NB_SORT - 1) / NB_SORT;
  int s = b*per, e_end = s + per; if (e_end > E) e_end = E;
  __shared__ int cur[SORT_BINS];
  for (int base = 0; base < Nn; base += SORT_BINS){
    for (int i = threadIdx.x; i < SORT_BINS; i += 256) cur[i] = 0;
    __syncthreads();
    for (int e = s + threadIdx.x; e < e_end; e += 256){
      int d = dst[e] - base;
      if (d >= 0 && d < SORT_BINS){
        int lr = atomicAdd(&cur[d], 1);
        eidx[rp[base + d] + part[(size_t)b*Nn + base + d] + lr] = e;
      }
    }
    __syncthreads();
  }
}

// ======== FAST PATH (all f32) ========

// node GEMMs (f32): uu = x@W1d + b1 ; vv = x@W1bot
template<int CP, int C>
__launch_bounds__(256)
__global__ void knode_f32(const float* __restrict__ W1d, const float* __restrict__ W1b,
                          const float* __restrict__ b1, const float* __restrict__ x,
                          float* __restrict__ uu, float* __restrict__ vv, int Nn){
  constexpr int NP = C / 64;
  __shared__ float A[16][CP + 1];
  int t = threadIdx.x, el = t & 15, grp = t >> 4;
  int r0 = blockIdx.x * 16;
  for (int idx = t; idx < 16*CP; idx += 256){
    int r = idx / CP, k = idx - r*CP;
    int rr = r0 + r;
    A[r][k] = (rr < Nn) ? x[(size_t)rr*CP + k] : 0.f;
  }
  __syncthreads();
  float au[NP][4], av[NP][4];
  #pragma unroll
  for (int p = 0; p < NP; ++p)
    #pragma unroll
    for (int i = 0; i < 4; ++i){
      au[p][i] = b1[p*64 + grp*4 + i];
      av[p][i] = 0.f;
    }
  #pragma unroll 2
  for (int k = 0; k < CP; ++k){
    float a = A[el][k];
    #pragma unroll
    for (int p = 0; p < NP; ++p){
      float4 wd = *reinterpret_cast<const float4*>(&W1d[(size_t)k*C + p*64 + grp*4]);
      float4 wb = *reinterpret_cast<const float4*>(&W1b[(size_t)k*C + p*64 + grp*4]);
      au[p][0] = fmaf(a, wd.x, au[p][0]); au[p][1] = fmaf(a, wd.y, au[p][1]);
      au[p][2] = fmaf(a, wd.z, au[p][2]); au[p][3] = fmaf(a, wd.w, au[p][3]);
      av[p][0] = fmaf(a, wb.x, av[p][0]); av[p][1] = fmaf(a, wb.y, av[p][1]);
      av[p][2] = fmaf(a, wb.z, av[p][2]); av[p][3] = fmaf(a, wb.w, av[p][3]);
    }
  }
  int rr = r0 + el;
  if (rr < Nn){
    #pragma unroll
    for (int p = 0; p < NP; ++p){
      int c = p*64 + grp*4;
      float4 ou; ou.x = au[p][0]; ou.y = au[p][1]; ou.z = au[p][2]; ou.w = au[p][3];
      float4 ov; ov.x = av[p][0]; ov.y = av[p][1]; ov.z = av[p][2]; ov.w = av[p][3];
      *reinterpret_cast<float4*>(&uu[(size_t)rr*C + c]) = ou;
      *reinterpret_cast<float4*>(&vv[(size_t)rr*C + c]) = ov;
    }
  }
}

// BN1 stats: sum/sumsq of relu(uu_i + vv_j) over all edges, per channel.
template<int C>
__launch_bounds__(256)
__global__ void kh1stats(const float* __restrict__ uu, const float* __restrict__ vv,
                         const int* __restrict__ src, const int* __restrict__ dst,
                         const int* __restrict__ eidx, int E, float* __restrict__ statp)
{
  constexpr int CLOG  = (C==64)?6:(C==128)?7:8;
  constexpr int RSTEP = 256 >> CLOG;
  const int t = threadIdx.x;
  const int kcol = t & (C-1), rb = t >> CLOG;
  int per = (E + gridDim.x - 1) / gridDim.x;
  int s0 = blockIdx.x * per;
  int s1 = s0 + per; if (s1 > E) s1 = E;
  float sa = 0.f, qa = 0.f;
  for (int es = s0 + rb; es < s1; es += RSTEP){
    int e = eidx[es];
    int i = dst[e], j = src[e];
    float a = fmaxf(uu[(size_t)i*C + kcol] + vv[(size_t)j*C + kcol], 0.f);
    sa += a; qa += a*a;
  }
  __shared__ float red[256];
  red[t] = sa;
  __syncthreads();
  if (t < C){
    float x = 0.f;
    #pragma unroll
    for (int r = 0; r < RSTEP; ++r) x += red[t + r*C];
    statp[(size_t)blockIdx.x*2*C + t] = x;
  }
  __syncthreads();
  red[t] = qa;
  __syncthreads();
  if (t < C){
    float x = 0.f;
    #pragma unroll
    for (int r = 0; r < RSTEP; ++r) x += red[t + r*C];
    statp[(size_t)blockIdx.x*2*C + C + t] = x;
  }
}

// fused layer-2 (f32, TE=32, EPL=2): gather H1, GEMM, stats, per-node max
// via LDS int atomicMax (values >= 0 after relu; max is order-independent).
template<int C>
__launch_bounds__(256)
__global__ void kfused_g2(const float* __restrict__ W2, const float* __restrict__ b2,
                          const float* __restrict__ sc1, const float* __restrict__ sh1,
                          const float* __restrict__ uu, const float* __restrict__ vv,
                          const int* __restrict__ src, const int* __restrict__ dst,
                          const int* __restrict__ eidx, const int* __restrict__ rp,
                          int Nn, float* __restrict__ nodemax, float* __restrict__ statp)
{
  constexpr int NT  = 16;
  constexpr int TE  = 32;
  constexpr int EPL = 2;
  constexpr int NP  = C / 64;
  __shared__ float H1[TE][C + 1];
  __shared__ int   nm[NT*C];
  __shared__ float red[16][64];
  __shared__ int Si[TE], Sj[TE], LNs[TE];

  int t = threadIdx.x, el = t & 15, grp = t >> 4;
  int n0 = blockIdx.x * NT;
  int e_begin = rp[n0];
  int e_end   = rp[n0 + NT];

  for (int i = t; i < NT*C; i += 256) nm[i] = 0;

  float sv[NP][4], qv[NP][4];
  #pragma unroll
  for (int p = 0; p < NP; ++p)
    #pragma unroll
    for (int i = 0; i < 4; ++i){ sv[p][i] = 0.f; qv[p][i] = 0.f; }

  for (int tile = e_begin; tile < e_end; tile += TE){
    int nrows = e_end - tile; if (nrows > TE) nrows = TE;
    __syncthreads();                 // prev tile's H1 readers + nm init done
    if (t < TE){
      if (t < nrows){
        int e = eidx[tile + t];
        int d_ = dst[e];
        Si[t] = d_; Sj[t] = src[e];
        int lnv = d_ - n0;
        LNs[t] = (lnv < 0) ? 0 : (lnv > NT-1 ? NT-1 : lnv);
      } else { Si[t] = 0; Sj[t] = 0; LNs[t] = 0; }
    }
    __syncthreads();
    // H1 gather
    for (int idx = t; idx < TE*C; idx += 256){
      int r = idx / C, c = idx - r*C;
      float v = 0.f;
      if (r < nrows){
        int ii = Si[r], jj = Sj[r];
        v = fmaxf(uu[(size_t)ii*C + c] + vv[(size_t)jj*C + c], 0.f) * sc1[c] + sh1[c];
      }
      H1[r][c] = v;
    }
    __syncthreads();
    // layer-2 GEMM (EPL=2) + stats + per-node atomicMax
    float acc[NP][EPL][4];
    #pragma unroll
    for (int p = 0; p < NP; ++p)
      #pragma unroll
      for (int i = 0; i < 4; ++i){
        float b = b2[p*64 + grp*4 + i];
        #pragma unroll
        for (int q = 0; q < EPL; ++q) acc[p][q][i] = b;
      }
    #pragma unroll 2
    for (int k = 0; k < C; ++k){
      float a[EPL];
      #pragma unroll
      for (int q = 0; q < EPL; ++q) a[q] = H1[el + q*16][k];
      #pragma unroll
      for (int p = 0; p < NP; ++p){
        float4 w = *reinterpret_cast<const float4*>(&W2[(size_t)k*C + p*64 + grp*4]);
        #pragma unroll
        for (int q = 0; q < EPL; ++q){
          acc[p][q][0] = fmaf(a[q], w.x, acc[p][q][0]);
          acc[p][q][1] = fmaf(a[q], w.y, acc[p][q][1]);
          acc[p][q][2] = fmaf(a[q], w.z, acc[p][q][2]);
          acc[p][q][3] = fmaf(a[q], w.w, acc[p][q][3]);
        }
      }
    }
    #pragma unroll
    for (int q = 0; q < EPL; ++q){
      int row = el + q*16;
      if (row < nrows){
        int base = LNs[row]*C;
        #pragma unroll
        for (int p = 0; p < NP; ++p){
          int c = p*64 + grp*4;
          #pragma unroll
          for (int i = 0; i < 4; ++i){
            float v = fmaxf(acc[p][q][i], 0.f);
            sv[p][i] += v; qv[p][i] += v*v;
            atomicMax(&nm[base + c + i], __float_as_int(v));
          }
        }
      }
    }
  }
  __syncthreads();
  for (int idx = t; idx < NT*C; idx += 256){
    int ln = idx / C, c = idx - ln*C;
    nodemax[(size_t)(n0+ln)*C + c] = __int_as_float(nm[idx]);
  }
  for (int p = 0; p < NP; ++p){
    __syncthreads();
    #pragma unroll
    for (int i = 0; i < 4; ++i) red[el][grp*4 + i] = sv[p][i];
    __syncthreads();
    if (t < 64){
      float a = 0.f;
      for (int e2 = 0; e2 < 16; ++e2) a += red[e2][t];
      statp[(size_t)blockIdx.x*2*C + p*64 + t] = a;
    }
    __syncthreads();
    #pragma unroll
    for (int i = 0; i < 4; ++i) red[el][grp*4 + i] = qv[p][i];
    __syncthreads();
    if (t < 64){
      float a = 0.f;
      for (int e2 = 0; e2 < 16; ++e2) a += red[e2][t];
      statp[(size_t)blockIdx.x*2*C + C + p*64 + t] = a;
    }
  }
}

// ======== PROVEN f32 kernels (fallback path) ========

template<int CIN, int C, int MODE>
__launch_bounds__(256)
__global__ void kstats1(const float* __restrict__ W1, const float* __restrict__ b1,
                        const float* __restrict__ in0, const float* __restrict__ posf,
                        const float* __restrict__ featf, const int* __restrict__ src,
                        const int* __restrict__ dst, int E, float* __restrict__ statp){
  constexpr int NP = C / 64;
  constexpr int CP = CIN / 2;
  __shared__ float A1[32][CIN + 1];
  __shared__ int Si[32], Sj[32];
  __shared__ float red[16][64];
  int t = threadIdx.x, el = t & 15, grp = t >> 4;
  float sv[NP][4], qv[NP][4];
  #pragma unroll
  for (int p = 0; p < NP; ++p)
    #pragma unroll
    for (int i = 0; i < 4; ++i){ sv[p][i] = 0.f; qv[p][i] = 0.f; }

  int ntiles = (E + 31) / 32;
  for (int tt = blockIdx.x; tt < ntiles; tt += gridDim.x){
    int tile = tt * 32;
    int nrows = E - tile; if (nrows > 32) nrows = 32;
    __syncthreads();
    if (t < 32){
      if (t < nrows){ Si[t] = dst[tile + t]; Sj[t] = src[tile + t]; }
      else { Si[t] = 0; Sj[t] = 0; }
    }
    __syncthreads();
    for (int idx = t; idx < 32*CIN; idx += 256){
      int r = idx / CIN, k = idx - r*CIN;
      float v = 0.f;
      if (r < nrows){
        int i = Si[r], j = Sj[r];
        v = (k < CP) ? in0[(size_t)i*CP + k]
                     : in0[(size_t)j*CP + (k-CP)] - in0[(size_t)i*CP + (k-CP)];
      }
      A1[r][k] = v;
    }
    __syncthreads();
    float acc[NP][2][4];
    #pragma unroll
    for (int p = 0; p < NP; ++p)
      #pragma unroll
      for (int i = 0; i < 4; ++i){ float b = b1[p*64 + grp*4 + i]; acc[p][0][i] = b; acc[p][1][i] = b; }
    #pragma unroll 2
    for (int k = 0; k < CIN; ++k){
      float a0 = A1[el][k], a1 = A1[el+16][k];
      #pragma unroll
      for (int p = 0; p < NP; ++p){
        float4 w = *reinterpret_cast<const float4*>(&W1[(size_t)k*C + p*64 + grp*4]);
        acc[p][0][0] = fmaf(a0, w.x, acc[p][0][0]); acc[p][0][1] = fmaf(a0, w.y, acc[p][0][1]);
        acc[p][0][2] = fmaf(a0, w.z, acc[p][0][2]); acc[p][0][3] = fmaf(a0, w.w, acc[p][0][3]);
        acc[p][1][0] = fmaf(a1, w.x, acc[p][1][0]); acc[p][1][1] = fmaf(a1, w.y, acc[p][1][1]);
        acc[p][1][2] = fmaf(a1, w.z, acc[p][1][2]); acc[p][1][3] = fmaf(a1, w.w, acc[p][1][3]);
      }
    }
    #pragma unroll
    for (int p = 0; p < NP; ++p)
      #pragma unroll
      for (int q = 0; q < 2; ++q){
        int row = el + q*16;
        if (row < nrows){
          #pragma unroll
          for (int i = 0; i < 4; ++i){
            float v = fmaxf(acc[p][q][i], 0.f);
            sv[p][i] += v; qv[p][i] += v*v;
          }
        }
      }
  }
  for (int p = 0; p < NP; ++p){
    __syncthreads();
    #pragma unroll
    for (int i = 0; i < 4; ++i) red[el][grp*4 + i] = sv[p][i];
    __syncthreads();
    if (t < 64){
      float a = 0.f;
      for (int e2 = 0; e2 < 16; ++e2) a += red[e2][t];
      statp[(size_t)blockIdx.x*2*C + p*64 + t] = a;
    }
    __syncthreads();
    #pragma unroll
    for (int i = 0; i < 4; ++i) red[el][grp*4 + i] = qv[p][i];
    __syncthreads();
    if (t < 64){
      float a = 0.f;
      for (int e2 = 0; e2 < 16; ++e2) a += red[e2][t];
      statp[(size_t)blockIdx.x*2*C + C + p*64 + t] = a;
    }
  }
}

template<int CIN, int C, int TE>
__launch_bounds__(256)
__global__ void kfused(const float* __restrict__ W1, const float* __restrict__ b1,
                       const float* __restrict__ W2, const float* __restrict__ b2,
                       const float* __restrict__ sc1, const float* __restrict__ sh1,
                       const float* __restrict__ in0,
                       const int* __restrict__ src, const int* __restrict__ dst,
                       const int* __restrict__ eidx, const int* __restrict__ rp,
                       float* __restrict__ nodemax, float* __restrict__ statp)
{
  constexpr int NT  = 16;
  constexpr int EPL = TE / 16;
  constexpr int NP  = C / 64;
  constexpr int CP  = CIN / 2;
  __shared__ float A1[TE][CIN + 1];
  __shared__ float H1[TE][C + 1];
  __shared__ float NM[NT][C];
  __shared__ float red[16][64];
  __shared__ int Si[TE], Sj[TE];
  float* H2 = &A1[0][0];

  int t = threadIdx.x, el = t & 15, grp = t >> 4;
  int n0 = blockIdx.x * NT;
  int e_begin = rp[n0];
  int e_end   = rp[n0 + NT];

  for (int i = t; i < NT*C; i += 256) (&NM[0][0])[i] = -INFINITY;

  float s2[NP][4], q2[NP][4];
  #pragma unroll
  for (int p = 0; p < NP; ++p)
    #pragma unroll
    for (int i = 0; i < 4; ++i){ s2[p][i] = 0.f; q2[p][i] = 0.f; }

  for (int tile = e_begin; tile < e_end; tile += TE){
    int nrows = e_end - tile; if (nrows > TE) nrows = TE;
    __syncthreads();
    if (t < TE){
      if (t < nrows){ int e = eidx[tile + t]; Si[t] = dst[e]; Sj[t] = src[e]; }
      else { Si[t] = 0; Sj[t] = 0; }
    }
    __syncthreads();
    for (int idx = t; idx < TE*CIN; idx += 256){
      int r = idx / CIN, k = idx - r*CIN;
      float v = 0.f;
      if (r < nrows){
        int i = Si[r], j = Sj[r];
        v = (k < CP) ? in0[(size_t)i*CP + k]
                     : in0[(size_t)j*CP + (k-CP)] - in0[(size_t)i*CP + (k-CP)];
      }
      A1[r][k] = v;
    }
    __syncthreads();
    {
      float acc[NP][EPL][4];
      #pragma unroll
      for (int p = 0; p < NP; ++p)
        #pragma unroll
        for (int i = 0; i < 4; ++i){
          float b = b1[p*64 + grp*4 + i];
          #pragma unroll
          for (int q = 0; q < EPL; ++q) acc[p][q][i] = b;
        }
      #pragma unroll 2
      for (int k = 0; k < CIN; ++k){
        float a[EPL];
        #pragma unroll
        for (int q = 0; q < EPL; ++q) a[q] = A1[el + q*16][k];
        #pragma unroll
        for (int p = 0; p < NP; ++p){
          float4 w = *reinterpret_cast<const float4*>(&W1[(size_t)k*C + p*64 + grp*4]);
          #pragma unroll
          for (int q = 0; q < EPL; ++q){
            acc[p][q][0] = fmaf(a[q], w.x, acc[p][q][0]);
            acc[p][q][1] = fmaf(a[q], w.y, acc[p][q][1]);
            acc[p][q][2] = fmaf(a[q], w.z, acc[p][q][2]);
            acc[p][q][3] = fmaf(a[q], w.w, acc[p][q][3]);
          }
        }
      }
      #pragma unroll
      for (int p = 0; p < NP; ++p)
        #pragma unroll
        for (int q = 0; q < EPL; ++q){
          int row = el + q*16;
          if (row < nrows){
            int c = p*64 + grp*4;
            #pragma unroll
            for (int i = 0; i < 4; ++i)
              H1[row][c+i] = fmaxf(acc[p][q][i], 0.f) * sc1[c+i] + sh1[c+i];
          }
        }
    }
    __syncthreads();
    {
      float acc[NP][EPL][4];
      #pragma unroll
      for (int p = 0; p < NP; ++p)
        #pragma unroll
        for (int i = 0; i < 4; ++i){
          float b = b2[p*64 + grp*4 + i];
          #pragma unroll
          for (int q = 0; q < EPL; ++q) acc[p][q][i] = b;
        }
      #pragma unroll 2
      for (int k = 0; k < C; ++k){
        float a[EPL];
        #pragma unroll
        for (int q = 0; q < EPL; ++q) a[q] = H1[el + q*16][k];
        #pragma unroll
        for (int p = 0; p < NP; ++p){
          float4 w = *reinterpret_cast<const float4*>(&W2[(size_t)k*C + p*64 + grp*4]);
          #pragma unroll
          for (int q = 0; q < EPL; ++q){
            acc[p][q][0] = fmaf(a[q], w.x, acc[p][q][0]);
            acc[p][q][1] = fmaf(a[q], w.y, acc[p][q][1]);
            acc[p][q][2] = fmaf(a[q], w.z, acc[p][q][2]);
            acc[p][q][3] = fmaf(a[q], w.w, acc[p][q][3]);
          }
        }
      }
      #pragma unroll
      for (int p = 0; p < NP; ++p)
        #pragma unroll
        for (int q = 0; q < EPL; ++q){
          int row = el + q*16;
          if (row < nrows){
            int c = p*64 + grp*4;
            #pragma unroll
            for (int i = 0; i < 4; ++i){
              float v = fmaxf(acc[p][q][i], 0.f);
              s2[p][i] += v; q2[p][i] += v*v;
              H2[row*(C+1) + c + i] = v;
            }
          }
        }
    }
    __syncthreads();
    for (int idx = t; idx < NT*C; idx += 256){
      int ln = idx / C, c = idx - ln*C;
      int n = n0 + ln;
      int lo = rp[n];   if (lo < tile) lo = tile;
      int hi = rp[n+1]; if (hi > tile + nrows) hi = tile + nrows;
      lo -= tile; hi -= tile;
      if (lo < hi){
        float m = NM[ln][c];
        for (int r = lo; r < hi; ++r) m = fmaxf(m, H2[r*(C+1) + c]);
        NM[ln][c] = m;
      }
    }
  }
  __syncthreads();
  for (int idx = t; idx < NT*C; idx += 256){
    int ln = idx / C, c = idx - ln*C;
    nodemax[(size_t)(n0+ln)*C + c] = NM[ln][c];
  }
  for (int p = 0; p < NP; ++p){
    __syncthreads();
    #pragma unroll
    for (int i = 0; i < 4; ++i) red[el][grp*4 + i] = s2[p][i];
    __syncthreads();
    if (t < 64){
      float a = 0.f;
      for (int e2 = 0; e2 < 16; ++e2) a += red[e2][t];
      statp[(size_t)blockIdx.x*2*C + p*64 + t] = a;
    }
    __syncthreads();
    #pragma unroll
    for (int i = 0; i < 4; ++i) red[el][grp*4 + i] = q2[p][i];
    __syncthreads();
    if (t < 64){
      float a = 0.f;
      for (int e2 = 0; e2 < 16; ++e2) a += red[e2][t];
      statp[(size_t)blockIdx.x*2*C + C + p*64 + t] = a;
    }
  }
}

// ---------------- stats reduce + BN finalize ----------------
__global__ void kstatred(const float* __restrict__ statp, int nblk, int C,
                         float* __restrict__ gs, float* __restrict__ gq){
  int c = blockIdx.x;
  float s = 0.f, q = 0.f;
  for (int b = threadIdx.x; b < nblk; b += 256){
    s += statp[(size_t)b*2*C + c];
    q += statp[(size_t)b*2*C + C + c];
  }
  __shared__ float ls[256], lq[256];
  ls[threadIdx.x] = s; lq[threadIdx.x] = q;
  __syncthreads();
  for (int o = 128; o; o >>= 1){
    if (threadIdx.x < o){ ls[threadIdx.x] += ls[threadIdx.x+o]; lq[threadIdx.x] += lq[threadIdx.x+o]; }
    __syncthreads();
  }
  if (threadIdx.x == 0){ gs[c] = ls[0]; gq[c] = lq[0]; }
}
__global__ void finalize_bn(const float* __restrict__ gs, const float* __restrict__ gq,
                            const float* __restrict__ g, const float* __restrict__ be,
                            float invR, float* __restrict__ sc, float* __restrict__ sh){
  int c = threadIdx.x;
  float m  = gs[c] * invR;
  float va = gq[c] * invR - m*m;
  float s  = g[c] * rsqrtf(va + 1e-5f);
  sc[c] = s;
  sh[c] = be[c] - m*s;
}

// ---------------- BN affine on node maxima ----------------
template<int C>
__global__ void kaffine(const float* __restrict__ nodemax, const int* __restrict__ rp,
                        const float* __restrict__ sc, const float* __restrict__ sh,
                        float* __restrict__ xo, int Nn){
  int i = blockIdx.x*256 + threadIdx.x;
  if (i >= Nn*C) return;
  int n = i / C, c = i - n*C;
  float v = 0.f;
  if (rp[n+1] > rp[n]) v = nodemax[i] * sc[c] + sh[c];
  xo[i] = v;
}

// ---------------- per-graph segment max of x123 (two-phase parallel) ----------------
__global__ void kxg_part(const float* __restrict__ x1, const float* __restrict__ x2,
                         const float* __restrict__ x3, const int* __restrict__ gptr,
                         float* __restrict__ xgpart){
  int g = blockIdx.x, ch = blockIdx.y;
  int t = threadIdx.x;
  int s = gptr[g], e = gptr[g+1];
  int len = e - s, per = (len + 31) / 32;
  int n0 = s + ch*per, n1 = n0 + per; if (n1 > e) n1 = e;
  float mx0 = -INFINITY, mx1 = -INFINITY;
  int c0 = t, c1 = t + 256;
  for (int n = n0; n < n1; ++n){
    float v0 = (c0 < 64)  ? x1[(size_t)n*64  + c0]
             : (c0 < 192) ? x2[(size_t)n*128 + (c0 - 64)]
                          : x3[(size_t)n*256 + (c0 - 192)];
    mx0 = fmaxf(mx0, v0);
    if (c1 < 448){
      float v1 = x3[(size_t)n*256 + (c1 - 192)];
      mx1 = fmaxf(mx1, v1);
    }
  }
  xgpart[(size_t)(g*32 + ch)*448 + c0] = mx0;
  if (c1 < 448) xgpart[(size_t)(g*32 + ch)*448 + c1] = mx1;
}
__global__ void kxg_red(const float* __restrict__ xgpart, const int* __restrict__ gptr,
                        float* __restrict__ xg){
  int g = blockIdx.x;
  int c = blockIdx.y * 256 + threadIdx.x;
  if (c >= 448) return;
  float mx = -INFINITY;
  for (int ch = 0; ch < 32; ++ch)
    mx = fmaxf(mx, xgpart[(size_t)(g*32 + ch)*448 + c]);
  xg[g*448 + c] = (gptr[g+1] > gptr[g] && !__builtin_isinf(mx)) ? mx : 0.f;
}

// ---------------- m1 ----------------
__launch_bounds__(256)
__global__ void km1(const float* __restrict__ Wf, const float* __restrict__ bias,
                    const float* __restrict__ x1, const float* __restrict__ x2,
                    const float* __restrict__ x3, float* __restrict__ x4p,
                    float* __restrict__ statp, int Nn){
  __shared__ float A[16][449];
  __shared__ float red[16][64];
  int t = threadIdx.x, el = t & 15, grp = t >> 4;
  int r0 = blockIdx.x * 16;
  for (int idx = t; idx < 16*448; idx += 256){
    int r = idx / 448, k = idx - r*448;
    int rr = r0 + r;
    float v = 0.f;
    if (rr < Nn)
      v = (k < 64)  ? x1[(size_t)rr*64  + k]
        : (k < 192) ? x2[(size_t)rr*128 + (k - 64)]
                    : x3[(size_t)rr*256 + (k - 192)];
    A[r][k] = v;
  }
  __syncthreads();
  float sv[4][4], qv[4][4];
  float acc[4][4];
  #pragma unroll
  for (int p = 0; p < 4; ++p)
    #pragma unroll
    for (int i = 0; i < 4; ++i){
      sv[p][i] = 0.f; qv[p][i] = 0.f;
      acc[p][i] = bias[p*64 + grp*4 + i];
    }
  #pragma unroll 2
  for (int k = 0; k < 448; ++k){
    float a = A[el][k];
    #pragma unroll
    for (int p = 0; p < 4; ++p){
      float4 w = *reinterpret_cast<const float4*>(&Wf[(size_t)k*256 + p*64 + grp*4]);
      acc[p][0] = fmaf(a, w.x, acc[p][0]); acc[p][1] = fmaf(a, w.y, acc[p][1]);
      acc[p][2] = fmaf(a, w.z, acc[p][2]); acc[p][3] = fmaf(a, w.w, acc[p][3]);
    }
  }
  int rr = r0 + el;
  #pragma unroll
  for (int p = 0; p < 4; ++p){
    if (rr < Nn){
      int c = p*64 + grp*4;
      float v0 = fmaxf(acc[p][0],0.f), v1 = fmaxf(acc[p][1],0.f);
      float v2 = fmaxf(acc[p][2],0.f), v3 = fmaxf(acc[p][3],0.f);
      sv[p][0]=v0; sv[p][1]=v1; sv[p][2]=v2; sv[p][3]=v3;
      qv[p][0]=v0*v0; qv[p][1]=v1*v1; qv[p][2]=v2*v2; qv[p][3]=v3*v3;
      float4 o; o.x=v0; o.y=v1; o.z=v2; o.w=v3;
      *reinterpret_cast<float4*>(&x4p[(size_t)rr*256 + c]) = o;
    }
  }
  for (int p = 0; p < 4; ++p){
    __syncthreads();
    #pragma unroll
    for (int i = 0; i < 4; ++i) red[el][grp*4 + i] = sv[p][i];
    __syncthreads();
    if (t < 64){
      float a = 0.f;
      for (int e2 = 0; e2 < 16; ++e2) a += red[e2][t];
      statp[(size_t)blockIdx.x*512 + p*64 + t] = a;
    }
    __syncthreads();
    #pragma unroll
    for (int i = 0; i < 4; ++i) red[el][grp*4 + i] = qv[p][i];
    __syncthreads();
    if (t < 64){
      float a = 0.f;
      for (int e2 = 0; e2 < 16; ++e2) a += red[e2][t];
      statp[(size_t)blockIdx.x*512 + 256 + p*64 + t] = a;
    }
  }
}

// ---------------- m2 + bn8 ----------------
__global__ void m2_mlp(const float* __restrict__ xg, const float* __restrict__ Wf,
                       const float* __restrict__ b, float* __restrict__ u_pre){
  __shared__ float row[448];
  int g = blockIdx.x, t = threadIdx.x;
  for (int k = t; k < 448; k += 256) row[k] = xg[g*448 + k];
  __syncthreads();
  float acc = b[t];
  #pragma unroll 4
  for (int k = 0; k < 448; ++k) acc = fmaf(row[k], Wf[(size_t)k*256 + t], acc);
  u_pre[g*256 + t] = fmaxf(acc, 0.f);
}
__global__ void bn8(const float* __restrict__ u_pre, const float* __restrict__ g,
                    const float* __restrict__ be, float* __restrict__ u_bn){
  int c = threadIdx.x;
  float s = 0.f, q = 0.f;
  for (int r = 0; r < 8; ++r){ float v = u_pre[r*256 + c]; s += v; q += v*v; }
  float m  = s * 0.125f;
  float va = q * 0.125f - m*m;
  float scl = g[c] * rsqrtf(va + 1e-5f);
  float sht = be[c] - m*scl;
  for (int r = 0; r < 8; ++r) u_bn[r*256 + c] = u_pre[r*256 + c]*scl + sht;
}

// ---------------- einsum ----------------
__global__ void keinsum(const float* __restrict__ x4p, const float* __restrict__ sc4,
                        const float* __restrict__ sh4, const float* __restrict__ hmf,
                        const int* __restrict__ gptr, float* __restrict__ x6part){
  int g = blockIdx.x, s32 = blockIdx.y, c = threadIdx.x;
  int s = gptr[g], e = gptr[g+1];
  int len = e - s;
  int per = (len + 31) / 32;
  int n0 = s + s32*per;
  int n1 = n0 + per; if (n1 > e) n1 = e;
  float scl = sc4[c], shf = sh4[c];
  float acc[24];
  #pragma unroll
  for (int i = 0; i < 24; ++i) acc[i] = 0.f;
  __shared__ float hrow[16][24];
  for (int nb = n0; nb < n1; nb += 16){
    int cntn = n1 - nb; if (cntn > 16) cntn = 16;
    __syncthreads();
    for (int i = threadIdx.x; i < cntn*24; i += 256)
      hrow[i/24][i%24] = hmf[(size_t)nb*24 + i];
    __syncthreads();
    for (int j = 0; j < cntn; ++j){
      float a = x4p[(size_t)(nb+j)*256 + c] * scl + shf;
      #pragma unroll
      for (int i = 0; i < 24; ++i) acc[i] = fmaf(a, hrow[j][i], acc[i]);
    }
  }
  #pragma unroll
  for (int i = 0; i < 24; ++i)
    x6part[((size_t)(g*32 + s32)*24 + i)*256 + c] = acc[i];
}
__global__ void keired(const float* __restrict__ x6part, float* __restrict__ x6p){
  int gk = blockIdx.x;
  int g = gk / 24, k = gk - g*24, c = threadIdx.x;
  float a = 0.f;
  for (int s32 = 0; s32 < 32; ++s32)
    a += x6part[((size_t)(g*32 + s32)*24 + k)*256 + c];
  x6p[(size_t)gk*256 + c] = a;
}

// ---------------- final linear + relu + BN (f32 output) ----------------
__global__ void lin_relu_k(const float* __restrict__ x6p, const float* __restrict__ u_bn,
                           const float* __restrict__ hs, const float* __restrict__ Wf,
                           const float* __restrict__ b, float* __restrict__ x7p){
  __shared__ float row[512];
  int r = blockIdx.x, t = threadIdx.x;
  int g = r / 24, kk = r - g*24;
  row[t]       = x6p[(size_t)r*256 + t];
  row[256 + t] = u_bn[g*256 + t] * hs[g*24 + kk];
  __syncthreads();
  float acc = b[t];
  #pragma unroll 4
  for (int k = 0; k < 512; ++k) acc = fmaf(row[k], Wf[(size_t)k*256 + t], acc);
  x7p[(size_t)r*256 + t] = fmaxf(acc, 0.f);
}
__global__ void final_bn_k(const float* __restrict__ x7p, const float* __restrict__ g,
                           const float* __restrict__ be, float* __restrict__ out){
  int c = threadIdx.x;
  float s = 0.f, q = 0.f;
  for (int r = 0; r < 192; ++r){ float v = x7p[(size_t)r*256 + c]; s += v; q += v*v; }
  const float inv = 1.f / 192.f;
  float m  = s * inv;
  float va = q * inv - m*m;
  float scl = g[c] * rsqrtf(va + 1e-5f);
  float sht = be[c] - m*scl;
  for (int r = 0; r < 192; ++r)
    out[(size_t)r*256 + c] = x7p[(size_t)r*256 + c]*scl + sht;
}

__global__ void kerr(float* out, float code){ if (threadIdx.x == 0) out[0] = code; }

extern "C" void kernel_launch(void* const* d_in, const int* in_sizes, int n_in,
                              void* d_out, int out_size, void* d_ws, size_t ws_size,
                              hipStream_t stream)
{
  const int N = in_sizes[0] / 3;
  const int E = in_sizes[3] / 2;
  float* outf = (float*)d_out;

  // ---- host-side input-map verification ----
  {
    const int co_[3] = {64,128,256};
    int exp41[41];
    exp41[0]=N*3; exp41[1]=N*61; exp41[2]=N*24; exp41[3]=2*E; exp41[4]=N;
    int idx=5;
    for (int i=0;i<3;++i){
      int ci = (i==0)?128:(i==1)?128:256;
      exp41[idx++]=ci*co_[i]; exp41[idx++]=co_[i]; exp41[idx++]=co_[i]; exp41[idx++]=co_[i];
      exp41[idx++]=co_[i]*co_[i]; exp41[idx++]=co_[i]; exp41[idx++]=co_[i]; exp41[idx++]=co_[i];
    }
    for (int r=0;r<2;++r){ exp41[idx++]=448*256; exp41[idx++]=256; exp41[idx++]=256; exp41[idx++]=256; }
    exp41[idx++]=512*256; exp41[idx++]=256; exp41[idx++]=256; exp41[idx++]=256;
    int bad = -1;
    if (n_in != 41) bad = 99;
    else for (int i=0;i<41;++i) if (in_sizes[i] != exp41[i]){ bad = i; break; }
    if (bad >= 0){
      kerr<<<1, 64, 0, stream>>>(outf, 100000.f + (float)bad);
      return;
    }
  }

  const int*  tei   = (const int*)d_in[3];
  const int*  batch = (const int*)d_in[4];
  const int*  srcp  = tei;
  const int*  dstp  = tei + E;

  char* base = (char*)d_ws;
  size_t off = 0;
  auto alloc = [&](size_t bytes) -> void* {
    void* p = base + off;
    off = (off + bytes + 255) & ~((size_t)255);
    return p;
  };

  int* flag = (int*)alloc(256);

  float* posf  = (float*)alloc((size_t)N*3*4);
  float* featf = (float*)alloc((size_t)N*61*4);
  float* hmf   = (float*)alloc((size_t)N*24*4);
  float* x0f   = (float*)alloc((size_t)N*64*4);
  float* w1f[3]; float* w2f[3];
  float* b1f[3]; float* g1f[3]; float* be1f[3];
  float* b2ff[3]; float* g2f[3]; float* be2f[3];
  float* s1a[3]; float* h1a[3]; float* s2a[3]; float* h2a[3];
  const int cin1[3] = {128, 128, 256};
  const int co[3]   = {64, 128, 256};
  for (int i = 0; i < 3; ++i){
    w1f[i]  = (float*)alloc((size_t)cin1[i]*co[i]*4);
    w2f[i]  = (float*)alloc((size_t)co[i]*co[i]*4);
    b1f[i]  = (float*)alloc(co[i]*4);
    g1f[i]  = (float*)alloc(co[i]*4);
    be1f[i] = (float*)alloc(co[i]*4);
    b2ff[i] = (float*)alloc(co[i]*4);
    g2f[i]  = (float*)alloc(co[i]*4);
    be2f[i] = (float*)alloc(co[i]*4);
    s1a[i]  = (float*)alloc(co[i]*4);
    h1a[i]  = (float*)alloc(co[i]*4);
    s2a[i]  = (float*)alloc(co[i]*4);
    h2a[i]  = (float*)alloc(co[i]*4);
  }
  float* w1df = (float*)alloc((size_t)128*256*4);   // W1top - W1bot (max size)
  float* m1wf = (float*)alloc(448*256*4);
  float* m1bf = (float*)alloc(256*4);
  float* m1gf = (float*)alloc(256*4);
  float* m1bef= (float*)alloc(256*4);
  float* m2wf = (float*)alloc(448*256*4);
  float* m2bf = (float*)alloc(256*4);
  float* m2gf = (float*)alloc(256*4);
  float* m2bef= (float*)alloc(256*4);
  float* linwf= (float*)alloc(512*256*4);
  float* linbf= (float*)alloc(256*4);
  float* bngf = (float*)alloc(256*4);
  float* bnbf = (float*)alloc(256*4);

  float* x1 = (float*)alloc((size_t)N*64*4);
  float* x2 = (float*)alloc((size_t)N*128*4);
  float* nodemax = (float*)alloc((size_t)N*256*4);
  float* x4p = nodemax;                          // alias: nodemax dead before km1

  float* statp = (float*)alloc((size_t)3200*512*4);
  int* part = (int*)alloc((size_t)NB_SORT*N*4);
  int* eidx = (int*)alloc((size_t)E*4);
  int* rp   = (int*)alloc((size_t)(N+1)*4);
  int* cnt  = (int*)alloc((size_t)N*4);
  int* gptr = (int*)alloc(16*4);

  float* gs  = (float*)alloc(256*4);
  float* gq  = (float*)alloc(256*4);
  float* sc4 = (float*)alloc(256*4); float* sh4 = (float*)alloc(256*4);
  float* hs  = (float*)alloc(192*4);

  // ubuf: uu for all GCUs; x3 aliases it (x3 written only after GCU3 done)
  float* ubuf = (float*)alloc((size_t)N*256*4);
  float* x3 = ubuf;

  // vbuf: vv for all GCUs if it fits; post-GCU tail buffers always alias it
  const size_t tailFl = 1793536;                 // floats needed by tail buffers
  const size_t fastB  = (size_t)N*256*4;
  size_t off0 = off;
  int plan = (off0 + fastB + (1u<<20) <= ws_size) ? 1 : 0;
  float* vbuf = (float*)alloc(plan ? fastB : (tailFl*4 + 1024));
  float* x6part = vbuf;
  float* xgpart = vbuf + 1572864;
  float* x6p    = vbuf + 1687552;
  float* x7p    = vbuf + 1736704;
  float* u_pre  = vbuf + 1785856;
  float* u_bn   = vbuf + 1787904;
  float* xg     = vbuf + 1789952;
  (void)out_size;

  kdetect<<<1, 256, 0, stream>>>((const unsigned short*)d_in[0], flag);
  CTab tab;
  int ti = 0;
  auto add = [&](int idx, float* dstp_, int n){ tab.e[ti].s = d_in[idx]; tab.e[ti].d = dstp_; tab.e[ti].n = n; ++ti; };
  add(0, posf,  N*3);
  add(1, featf, N*61);
  add(2, hmf,   N*24);
  for (int i = 0; i < 3; ++i){
    int b0 = 5 + i*8;
    add(b0+0, w1f[i],  cin1[i]*co[i]);
    add(b0+1, b1f[i],  co[i]);
    add(b0+2, g1f[i],  co[i]);
    add(b0+3, be1f[i], co[i]);
    add(b0+4, w2f[i],  co[i]*co[i]);
    add(b0+5, b2ff[i], co[i]);
    add(b0+6, g2f[i],  co[i]);
    add(b0+7, be2f[i], co[i]);
  }
  add(29, m1wf, 448*256); add(30, m1bf, 256); add(31, m1gf, 256); add(32, m1bef, 256);
  add(33, m2wf, 448*256); add(34, m2bf, 256); add(35, m2gf, 256); add(36, m2bef, 256);
  add(37, linwf, 512*256); add(38, linbf, 256); add(39, bngf, 256); add(40, bnbf, 256);
  kconv<<<dim3(64, 39), 256, 0, stream>>>(tab, flag);

  kpack0<<<(N*64 + 255)/256, 256, 0, stream>>>(posf, featf, x0f, N);

  kgptr<<<1, 64, 0, stream>>>(batch, N, gptr);
  khs<<<8, 256, 0, stream>>>(hmf, gptr, hs);

  // ---- parallel counting sort of edges by dst ----
  const int gridN = (N + 255)/256;
  khist<<<NB_SORT, 256, 0, stream>>>(dstp, E, N, part);
  kcnt<<<gridN, 256, 0, stream>>>(part, N, cnt);
  kscan<<<1, 256, 0, stream>>>(cnt, N, rp);
  kpre<<<gridN, 256, 0, stream>>>(part, N);
  kscatter<<<NB_SORT, 256, 0, stream>>>(dstp, E, N, part, rp, eidx);

  const int NBKF = N / 16;
  const int nblk16 = (N + 15) / 16;
  const float invE = 1.f / (float)E;

  if (plan){
    float* uu = ubuf;
    float* vv = vbuf;
    // ---- GCU1: CP=64, C=64 ----
    kwd<<<(64*64 + 255)/256, 256, 0, stream>>>(w1f[0], w1df, 64*64);
    knode_f32<64,64><<<nblk16, 256, 0, stream>>>(w1df, w1f[0] + 64*64, b1f[0], x0f, uu, vv, N);
    kh1stats<64><<<1024, 256, 0, stream>>>(uu, vv, srcp, dstp, eidx, E, statp);
    kstatred<<<64, 256, 0, stream>>>(statp, 1024, 64, gs, gq);
    finalize_bn<<<1, 64, 0, stream>>>(gs, gq, g1f[0], be1f[0], invE, s1a[0], h1a[0]);
    kfused_g2<64><<<NBKF, 256, 0, stream>>>(w2f[0], b2ff[0], s1a[0], h1a[0],
        uu, vv, srcp, dstp, eidx, rp, N, nodemax, statp);
    kstatred<<<64, 256, 0, stream>>>(statp, NBKF, 64, gs, gq);
    finalize_bn<<<1, 64, 0, stream>>>(gs, gq, g2f[0], be2f[0], invE, s2a[0], h2a[0]);
    kaffine<64><<<(N*64 + 255)/256, 256, 0, stream>>>(nodemax, rp, s2a[0], h2a[0], x1, N);
    // ---- GCU2: CP=64, C=128 ----
    kwd<<<(64*128 + 255)/256, 256, 0, stream>>>(w1f[1], w1df, 64*128);
    knode_f32<64,128><<<nblk16, 256, 0, stream>>>(w1df, w1f[1] + 64*128, b1f[1], x1, uu, vv, N);
    kh1stats<128><<<1024, 256, 0, stream>>>(uu, vv, srcp, dstp, eidx, E, statp);
    kstatred<<<128, 256, 0, stream>>>(statp, 1024, 128, gs, gq);
    finalize_bn<<<1, 128, 0, stream>>>(gs, gq, g1f[1], be1f[1], invE, s1a[1], h1a[1]);
    kfused_g2<128><<<NBKF, 256, 0, stream>>>(w2f[1], b2ff[1], s1a[1], h1a[1],
        uu, vv, srcp, dstp, eidx, rp, N, nodemax, statp);
    kstatred<<<128, 256, 0, stream>>>(statp, NBKF, 128, gs, gq);
    finalize_bn<<<1, 128, 0, stream>>>(gs, gq, g2f[1], be2f[1], invE, s2a[1], h2a[1]);
    kaffine<128><<<(N*128 + 255)/256, 256, 0, stream>>>(nodemax, rp, s2a[1], h2a[1], x2, N);
    // ---- GCU3: CP=128, C=256 ----
    kwd<<<(128*256 + 255)/256, 256, 0, stream>>>(w1f[2], w1df, 128*256);
    knode_f32<128,256><<<nblk16, 256, 0, stream>>>(w1df, w1f[2] + 128*256, b1f[2], x2, uu, vv, N);
    kh1stats<256><<<1024, 256, 0, stream>>>(uu, vv, srcp, dstp, eidx, E, statp);
    kstatred<<<256, 256, 0, stream>>>(statp, 1024, 256, gs, gq);
    finalize_bn<<<1, 256, 0, stream>>>(gs, gq, g1f[2], be1f[2], invE, s1a[2], h1a[2]);
    kfused_g2<256><<<NBKF, 256, 0, stream>>>(w2f[2], b2ff[2], s1a[2], h1a[2],
        uu, vv, srcp, dstp, eidx, rp, N, nodemax, statp);
    kstatred<<<256, 256, 0, stream>>>(statp, NBKF, 256, gs, gq);
    finalize_bn<<<1, 256, 0, stream>>>(gs, gq, g2f[2], be2f[2], invE, s2a[2], h2a[2]);
    kaffine<256><<<(N*256 + 255)/256, 256, 0, stream>>>(nodemax, rp, s2a[2], h2a[2], x3, N);
  } else {
    // ---- fallback: known-good R10 f32 path ----
    const int NBK1 = 1024;
    kstats1<128,64,0><<<NBK1, 256, 0, stream>>>(w1f[0], b1f[0], x0f, nullptr, nullptr,
        srcp, dstp, E, statp);
    kstatred<<<64, 256, 0, stream>>>(statp, NBK1, 64, gs, gq);
    finalize_bn<<<1, 64, 0, stream>>>(gs, gq, g1f[0], be1f[0], invE, s1a[0], h1a[0]);
    kfused<128,64,32><<<NBKF, 256, 0, stream>>>(w1f[0], b1f[0], w2f[0], b2ff[0],
        s1a[0], h1a[0], x0f, srcp, dstp, eidx, rp, nodemax, statp);
    kstatred<<<64, 256, 0, stream>>>(statp, NBKF, 64, gs, gq);
    finalize_bn<<<1, 64, 0, stream>>>(gs, gq, g2f[0], be2f[0], invE, s2a[0], h2a[0]);
    kaffine<64><<<(N*64 + 255)/256, 256, 0, stream>>>(nodemax, rp, s2a[0], h2a[0], x1, N);

    kstats1<128,128,0><<<NBK1, 256, 0, stream>>>(w1f[1], b1f[1], x1, nullptr, nullptr,
        srcp, dstp, E, statp);
    kstatred<<<128, 256, 0, stream>>>(statp, NBK1, 128, gs, gq);
    finalize_bn<<<1, 128, 0, stream>>>(gs, gq, g1f[1], be1f[1], invE, s1a[1], h1a[1]);
    kfused<128,128,32><<<NBKF, 256, 0, stream>>>(w1f[1], b1f[1], w2f[1], b2ff[1],
        s1a[1], h1a[1], x1, srcp, dstp, eidx, rp, nodemax, statp);
    kstatred<<<128, 256, 0, stream>>>(statp, NBKF, 128, gs, gq);
    finalize_bn<<<1, 128, 0, stream>>>(gs, gq, g2f[1], be2f[1], invE, s2a[1], h2a[1]);
    kaffine<128><<<(N*128 + 255)/256, 256, 0, stream>>>(nodemax, rp, s2a[1], h2a[1], x2, N);

    kstats1<256,256,0><<<NBK1, 256, 0, stream>>>(w1f[2], b1f[2], x2, nullptr, nullptr,
        srcp, dstp, E, statp);
    kstatred<<<256, 256, 0, stream>>>(statp, NBK1, 256, gs, gq);
    finalize_bn<<<1, 256, 0, stream>>>(gs, gq, g1f[2], be1f[2], invE, s1a[2], h1a[2]);
    kfused<256,256,16><<<NBKF, 256, 0, stream>>>(w1f[2], b1f[2], w2f[2], b2ff[2],
        s1a[2], h1a[2], x2, srcp, dstp, eidx, rp, nodemax, statp);
    kstatred<<<256, 256, 0, stream>>>(statp, NBKF, 256, gs, gq);
    finalize_bn<<<1, 256, 0, stream>>>(gs, gq, g2f[2], be2f[2], invE, s2a[2], h2a[2]);
    kaffine<256><<<(N*256 + 255)/256, 256, 0, stream>>>(nodemax, rp, s2a[2], h2a[2], x3, N);
  }

  // graph pooling (parallel two-phase)
  kxg_part<<<dim3(8, 32), 256, 0, stream>>>(x1, x2, x3, gptr, xgpart);
  kxg_red<<<dim3(8, 2), 256, 0, stream>>>(xgpart, gptr, xg);

  km1<<<NBKF, 256, 0, stream>>>(m1wf, m1bf, x1, x2, x3, x4p, statp, N);
  kstatred<<<256, 256, 0, stream>>>(statp, NBKF, 256, gs, gq);
  finalize_bn<<<1, 256, 0, stream>>>(gs, gq, m1gf, m1bef, 1.f/(float)N, sc4, sh4);

  m2_mlp<<<8, 256, 0, stream>>>(xg, m2wf, m2bf, u_pre);
  bn8<<<1, 256, 0, stream>>>(u_pre, m2gf, m2bef, u_bn);

  keinsum<<<dim3(8, 32), 256, 0, stream>>>(x4p, sc4, sh4, hmf, gptr, x6part);
  keired<<<192, 256, 0, stream>>>(x6part, x6p);

  lin_relu_k<<<192, 256, 0, stream>>>(x6p, u_bn, hs, linwf, linbf, x7p);
  final_bn_k<<<1, 256, 0, stream>>>(x7p, bngf, bnbf, outf);
}